// Round 13
// baseline (284.052 us; speedup 1.0000x reference)
//
#include <hip/hip_runtime.h>

// NeighborhoodAttention2D: B=8, C=512, H=W=56, heads=16, d=32, KSZ=7
// Round 21: raise qkv GEMM arithmetic intensity (LDS-read-BW bound).
//  r20 post-mortem: MfmaUtil pinned at 22% across dbuf/vmcnt/occupancy fixes.
//  Model: per-wave 128x32 output = 25.6 FLOP/B from LDS ~ breakeven with the
//  measured 85 B/cyc ds_read_b128 rate shared with staging writes -> frag-read
//  BANDWIDTH is the wall, not latency.
//  Fix: 2-wave (128-thread) blocks, per-wave output 128n x 64px (acc[8][4]):
//  intensity 42.7 FLOP/B (+67%), total LDS reads 1.5GB -> 0.9GB; LDS 40KB
//  -> exactly 4 blocks/CU = 4 independent pipelines. vmcnt(10) counted wait.
//  attn/proj/prep/fallbacks unchanged from green r20.

typedef unsigned short ushort_t;
typedef short bf16x8 __attribute__((ext_vector_type(8)));      // 8 bf16 = 4 VGPRs
typedef short bf16x4 __attribute__((ext_vector_type(4)));      // 4 bf16 = 2 VGPRs
typedef float f32x4 __attribute__((ext_vector_type(4)));       // MFMA C/D frag
typedef unsigned int uint4_t __attribute__((ext_vector_type(4)));
typedef unsigned int uint2_t __attribute__((ext_vector_type(2)));

#define BATCH 8
#define HEADS 16
#define HW 3136
#define HH 56
#define DD 32
#define CC 512
#define PLANE ((size_t)BATCH * HEADS * HW * DD)   // 12,845,056 elems (= B*C*HW)
#define OUT_TOT ((size_t)BATCH * CC * HW)
#define LP 40                                      // fallback-GEMM LDS pitch
#define LPG 32                                     // gload_lds GEMM pitch (linear rows)

// attention tile geometry
#define KT 14
#define KP 32
#define VPP 228

#define WQ_ELEMS (1536 * 512)
#define WP_ELEMS (512 * 512)

__device__ __forceinline__ ushort_t f2bf(float f) {
    union { float f; unsigned int i; } v; v.f = f;
    unsigned int r = v.i + 0x7FFFu + ((v.i >> 16) & 1u);   // RNE
    return (ushort_t)(r >> 16);
}
__device__ __forceinline__ unsigned int pack2(float a, float b) {
    return (unsigned int)f2bf(a) | ((unsigned int)f2bf(b) << 16);
}

__device__ __forceinline__ f32x4 mfma16x16x16(bf16x4 a, bf16x4 b, f32x4 c) {
#if __has_builtin(__builtin_amdgcn_mfma_f32_16x16x16bf16_1k)
    return __builtin_amdgcn_mfma_f32_16x16x16bf16_1k(a, b, c, 0, 0, 0);
#else
    f32x4 d;
    asm("v_mfma_f32_16x16x16_bf16 %0, %1, %2, %3" : "=v"(d) : "v"(a), "v"(b), "v"(c));
    return d;
#endif
}

// async global->LDS, 16B per lane; lds dest must be wave-linear (base + lane*16)
__device__ __forceinline__ void gload16(const ushort_t* g, ushort_t* l) {
    __builtin_amdgcn_global_load_lds(
        (const __attribute__((address_space(1))) unsigned int*)g,
        (__attribute__((address_space(3))) unsigned int*)l, 16, 0, 0);
}

__global__ __launch_bounds__(256) void zero_out_f32(float* __restrict__ out) {
    size_t idx = (size_t)blockIdx.x * 256 + threadIdx.x;
    if (idx < OUT_TOT) out[idx] = 0.f;
}

// ---------------- prep: both weight matrices f32 -> bf16, one launch ----------------
__global__ __launch_bounds__(256) void cvt_weights(const float* __restrict__ wa,
                                                   ushort_t* __restrict__ da, int n8a,
                                                   const float* __restrict__ wb,
                                                   ushort_t* __restrict__ db, int n8b) {
    int idx = blockIdx.x * 256 + threadIdx.x;
    const float* s;
    ushort_t* d;
    int i;
    if (idx < n8a) {
        s = wa; d = da; i = idx;
    } else {
        i = idx - n8a;
        if (i >= n8b) return;
        s = wb; d = db;
    }
    const float4* sp = (const float4*)s + (size_t)i * 2;
    float4 f0 = sp[0], f1 = sp[1];
    uint4_t u;
    u[0] = pack2(f0.x, f0.y);
    u[1] = pack2(f0.z, f0.w);
    u[2] = pack2(f1.x, f1.y);
    u[3] = pack2(f1.z, f1.w);
    *(uint4_t*)(d + (size_t)i * 8) = u;
}

// ---------------- prep: x [b][c][hw] f32 -> xbf [b][hw][c] bf16 ----------------
__global__ __launch_bounds__(256) void xpose_cvt(const float* __restrict__ x,
                                                 ushort_t* __restrict__ xb) {
    __shared__ ushort_t T[64 * 64];                // 8192 B
    int tid = threadIdx.x;
    int hw0 = blockIdx.x * 64;
    int c0 = blockIdx.y * 64;
    int b = blockIdx.z;

    int cr = tid >> 2, hq = tid & 3;
    const float* src = x + ((size_t)b * CC + c0 + cr) * HW + hw0 + hq * 16;
    float4 f0 = *(const float4*)(src);
    float4 f1 = *(const float4*)(src + 4);
    float4 f2 = *(const float4*)(src + 8);
    float4 f3 = *(const float4*)(src + 12);
    uint4_t u0, u1;
    u0[0] = pack2(f0.x, f0.y); u0[1] = pack2(f0.z, f0.w);
    u0[2] = pack2(f1.x, f1.y); u0[3] = pack2(f1.z, f1.w);
    u1[0] = pack2(f2.x, f2.y); u1[1] = pack2(f2.z, f2.w);
    u1[2] = pack2(f3.x, f3.y); u1[3] = pack2(f3.z, f3.w);
    int sw = ((cr >> 4) & 3) << 4;
    int col0 = (hq * 16) ^ sw;
    *(uint4_t*)&T[cr * 64 + col0] = u0;
    *(uint4_t*)&T[cr * 64 + col0 + 8] = u1;

    __syncthreads();

    int p = tid >> 2, cq = tid & 3;
    int pc = p ^ (cq << 4);
    unsigned vv[8];
    #pragma unroll
    for (int j = 0; j < 16; j += 2) {
        unsigned a = T[(cq * 16 + j) * 64 + pc];
        unsigned b2 = T[(cq * 16 + j + 1) * 64 + pc];
        vv[j >> 1] = a | (b2 << 16);
    }
    ushort_t* dst = xb + ((size_t)b * HW + hw0 + p) * CC + c0 + cq * 16;
    uint4_t w0, w1;
    w0[0] = vv[0]; w0[1] = vv[1]; w0[2] = vv[2]; w0[3] = vv[3];
    w1[0] = vv[4]; w1[1] = vv[5]; w1[2] = vv[6]; w1[3] = vv[7];
    *(uint4_t*)&dst[0] = w0;
    *(uint4_t*)&dst[8] = w1;
}

// ---------------- GEMM1 (bf16): qkv^T = wq (1536x512) . xb ([b][hw][c]) ----------
// 2-wave blocks, per-wave 128n x 64px (acc[8][4], intensity 42.7 FLOP/B);
// dbuf + counted vmcnt(10), raw barriers, XCD swizzle. LDS 40KB = 4 blocks/CU.
__global__ __launch_bounds__(128) void qkv_gemm_bf16(const ushort_t* __restrict__ xb,
                                                     const ushort_t* __restrict__ w,
                                                     ushort_t* __restrict__ qkv) {
    __shared__ __align__(16) ushort_t lds_p[2][256 * LPG];   // 2 x 16384 B
    __shared__ __align__(16) ushort_t lds_q[2][64 * LPG];    // 2 x  4096 B
    int tid = threadIdx.x;

    // T1 XCD swizzle: grid 49x6x8 = 2352 = 8 x 294; each XCD chunk = one batch b
    int lid = ((int)blockIdx.z * 6 + (int)blockIdx.y) * 49 + (int)blockIdx.x;
    int wl = (lid & 7) * 294 + (lid >> 3);
    int p0 = (wl % 49) * 64;
    int rest = wl / 49;
    int n0 = (rest % 6) * 256;
    int b = rest / 6;

    int lane = tid & 63, wv = tid >> 6;        // wv in {0,1}: 128-row half
    int quad = lane >> 4, l15 = lane & 15;

    f32x4 acc[8][4];
    #pragma unroll
    for (int i = 0; i < 8; ++i)
        #pragma unroll
        for (int jq = 0; jq < 4; ++jq) acc[i][jq] = (f32x4){0.f, 0.f, 0.f, 0.f};

    int swz = (l15 >> 1) & 3;                  // fragment-read swizzle (row->chunk)
    int cha = (quad ^ swz) * 8;                // swizzled k-octet for frag reads

    // per-thread staging descriptors (constant across kt); 128 threads
    int ca_row[8], ca_k8[8];
    #pragma unroll
    for (int r = 0; r < 8; ++r) {
        int c = r * 128 + tid;                 // A: 1024 chunks
        ca_row[r] = c >> 2;
        ca_k8[r] = ((c & 3) ^ ((c >> 3) & 3)) * 8;
    }
    int cb_row[2], cb_k8[2];
    #pragma unroll
    for (int r = 0; r < 2; ++r) {
        int c = r * 128 + tid;                 // B: 256 chunks
        cb_row[r] = c >> 2;
        cb_k8[r] = ((c & 3) ^ ((c >> 3) & 3)) * 8;
    }

    auto stage = [&](int buf, int ko) {
        #pragma unroll
        for (int r = 0; r < 8; ++r)
            gload16(w + (size_t)(n0 + ca_row[r]) * CC + ko + ca_k8[r],
                    &lds_p[buf][(r * 128 + tid) * 8]);
        #pragma unroll
        for (int r = 0; r < 2; ++r)
            gload16(xb + ((size_t)b * HW + p0 + cb_row[r]) * CC + ko + cb_k8[r],
                    &lds_q[buf][(r * 128 + tid) * 8]);
    };

    auto compute_tile = [&](int cur) {
        bf16x8 afrag[8], bfrag[4];
        #pragma unroll
        for (int i = 0; i < 8; ++i)
            afrag[i] = *(const bf16x8*)&lds_p[cur][(wv * 128 + i * 16 + l15) * LPG + cha];
        #pragma unroll
        for (int jq = 0; jq < 4; ++jq)
            bfrag[jq] = *(const bf16x8*)&lds_q[cur][(jq * 16 + l15) * LPG + cha];
        #pragma unroll
        for (int i = 0; i < 8; ++i)
            #pragma unroll
            for (int jq = 0; jq < 4; ++jq)
                acc[i][jq] = __builtin_amdgcn_mfma_f32_16x16x32_bf16(afrag[i], bfrag[jq],
                                                                     acc[i][jq], 0, 0, 0);
    };

    const int NKT = CC / 32;                   // 16
    // prologue: stage tile 0 into buffer 0, full drain once
    stage(0, 0);
    asm volatile("s_waitcnt vmcnt(0)" ::: "memory");
    __builtin_amdgcn_s_barrier();
    asm volatile("" ::: "memory");

    for (int kt = 0; kt < NKT - 1; ++kt) {
        int cur = kt & 1;
        stage(cur ^ 1, (kt + 1) * 32);
        // T4: wait ONLY for tile kt's 10 loads (oldest); kt+1's 10 stay in flight
        asm volatile("s_waitcnt vmcnt(10)" ::: "memory");
        __builtin_amdgcn_s_barrier();
        asm volatile("" ::: "memory");
        compute_tile(cur);
        asm volatile("" ::: "memory");
        __builtin_amdgcn_s_barrier();          // readers of buf[cur] done before next staging
        asm volatile("" ::: "memory");
    }
    asm volatile("s_waitcnt vmcnt(0)" ::: "memory");
    __builtin_amdgcn_s_barrier();
    asm volatile("" ::: "memory");
    compute_tile((NKT - 1) & 1);

    const float qscale = 0.17677669529663687f;   // 1/sqrt(32)
    #pragma unroll
    for (int i = 0; i < 8; ++i) {
        int nbase = n0 + wv * 128 + i * 16 + quad * 4;
        int which = nbase >> 9;
        int h = (nbase >> 5) & 15;
        int dch = nbase & 31;
        float sc = (which == 0) ? qscale : 1.0f;
        #pragma unroll
        for (int jq = 0; jq < 4; ++jq) {
            int pix = p0 + jq * 16 + l15;
            uint2_t v;
            v[0] = pack2(acc[i][jq][0] * sc, acc[i][jq][1] * sc);
            v[1] = pack2(acc[i][jq][2] * sc, acc[i][jq][3] * sc);
            ushort_t* dst = qkv + (size_t)which * PLANE +
                            ((((size_t)b * HEADS + h) * HW + pix) * DD + dch);
            *(uint2_t*)dst = v;
        }
    }
}

// ---------------- GEMM1 fallback (f32 inputs) ----------------
__global__ __launch_bounds__(256) void qkv_gemm_kernel(const float* __restrict__ x,
                                                       const float* __restrict__ w,
                                                       ushort_t* __restrict__ qkv) {
    __shared__ __align__(16) ushort_t lds_p[128 * LP];
    __shared__ __align__(16) ushort_t lds_q[64 * LP];
    const int K = CC;
    int tid = threadIdx.x;
    int b = blockIdx.z;
    int n0 = blockIdx.y * 128;
    int p0 = blockIdx.x * 64;
    int lane = tid & 63, wv = tid >> 6;
    int wp = wv & 1, wq = wv >> 1;
    int quad = lane >> 4, l15 = lane & 15;

    f32x4 acc[4][2];
    #pragma unroll
    for (int i = 0; i < 4; ++i)
        #pragma unroll
        for (int jq = 0; jq < 2; ++jq) acc[i][jq] = (f32x4){0.f, 0.f, 0.f, 0.f};

    int spx = tid & 63;
    int sk8 = (tid >> 6) * 8;

    for (int kt = 0; kt < K / 32; ++kt) {
        __syncthreads();
        #pragma unroll
        for (int r = 0; r < 2; ++r) {
            int chunk = tid + r * 256;
            int row = chunk >> 2, k8 = (chunk & 3) * 8;
            const float* src = w + (size_t)(n0 + row) * K + kt * 32 + k8;
            float4 f0 = *(const float4*)src;
            float4 f1 = *(const float4*)(src + 4);
            uint4_t u;
            u[0] = pack2(f0.x, f0.y);
            u[1] = pack2(f0.z, f0.w);
            u[2] = pack2(f1.x, f1.y);
            u[3] = pack2(f1.z, f1.w);
            *(uint4_t*)&lds_p[row * LP + k8] = u;
        }
        {
            const float* xcol = x + ((size_t)b * CC + kt * 32 + sk8) * HW + p0 + spx;
            float v0 = xcol[0];
            float v1 = xcol[(size_t)HW];
            float v2 = xcol[(size_t)2 * HW];
            float v3 = xcol[(size_t)3 * HW];
            float v4 = xcol[(size_t)4 * HW];
            float v5 = xcol[(size_t)5 * HW];
            float v6 = xcol[(size_t)6 * HW];
            float v7 = xcol[(size_t)7 * HW];
            uint4_t u;
            u[0] = pack2(v0, v1);
            u[1] = pack2(v2, v3);
            u[2] = pack2(v4, v5);
            u[3] = pack2(v6, v7);
            *(uint4_t*)&lds_q[spx * LP + sk8] = u;
        }
        __syncthreads();
        bf16x8 afrag[4], bfrag[2];
        #pragma unroll
        for (int i = 0; i < 4; ++i)
            afrag[i] = *(const bf16x8*)&lds_p[(wp * 64 + i * 16 + l15) * LP + quad * 8];
        #pragma unroll
        for (int jq = 0; jq < 2; ++jq)
            bfrag[jq] = *(const bf16x8*)&lds_q[(wq * 32 + jq * 16 + l15) * LP + quad * 8];
        #pragma unroll
        for (int i = 0; i < 4; ++i)
            #pragma unroll
            for (int jq = 0; jq < 2; ++jq)
                acc[i][jq] = __builtin_amdgcn_mfma_f32_16x16x32_bf16(afrag[i], bfrag[jq],
                                                                     acc[i][jq], 0, 0, 0);
    }
    const float qscale = 0.17677669529663687f;
    #pragma unroll
    for (int i = 0; i < 4; ++i) {
        int nbase = n0 + wp * 64 + i * 16 + quad * 4;
        int which = nbase >> 9;
        int h = (nbase >> 5) & 15;
        int dch = nbase & 31;
        float sc = (which == 0) ? qscale : 1.0f;
        #pragma unroll
        for (int jq = 0; jq < 2; ++jq) {
            int pix = p0 + wq * 32 + jq * 16 + l15;
            uint2_t v;
            v[0] = pack2(acc[i][jq][0] * sc, acc[i][jq][1] * sc);
            v[1] = pack2(acc[i][jq][2] * sc, acc[i][jq][3] * sc);
            ushort_t* dst = qkv + (size_t)which * PLANE +
                            ((((size_t)b * HEADS + h) * HW + pix) * DD + dch);
            *(uint2_t*)dst = v;
        }
    }
}

// ---------------- MFMA attention: one block per (b, h, 8x8 query tile) ----------------
__global__ __launch_bounds__(256, 4) void attn_mfma(ushort_t* __restrict__ qkv,
                                                    const float* __restrict__ rpb) {
    __shared__ __align__(16) ushort_t Klds[224 * KP];        // 14336 B, [kk][d]
    __shared__ __align__(16) ushort_t Vlds[DD * VPP];        // 14592 B, [d][kk]
    __shared__ float rpbl[169];                              //   676 B

    int tid = threadIdx.x;

    // T1 XCD swizzle: grid 49x16x8 = 6272 = 8 x 784; each XCD chunk = one batch b
    int lid = ((int)blockIdx.z * 16 + (int)blockIdx.y) * 49 + (int)blockIdx.x;
    int wl = (lid & 7) * 784 + (lid >> 3);
    int tile = wl % 49;
    int rest = wl / 49;
    int h = rest % 16;
    int b = rest / 16;

    int ti = tile / 7, tj = tile - ti * 7;
    int i0 = ti * 8, j0 = tj * 8;
    int kr0 = min(max(i0 - 3, 0), HH - 14);
    int kc0 = min(max(j0 - 3, 0), HH - 14);

    const ushort_t* qp = qkv + (((size_t)b * HEADS + h) * HW) * DD;
    const ushort_t* kp = qp + PLANE;
    const ushort_t* vp = qp + 2 * PLANE;

    if (tid < 169) rpbl[tid] = rpb[h * 169 + tid];

    #pragma unroll
    for (int r = 0; r < 4; ++r) {
        int idx = tid + r * 256;
        if (idx < 784) {
            int u = idx / 56;
            int rem = idx - u * 56;
            int w = rem >> 2, d8 = (rem & 3) << 3;
            const ushort_t* src = kp + ((size_t)((kr0 + u) * HH + kc0 + w)) * DD + d8;
            *(uint4_t*)&Klds[(u * 16 + w) * KP + d8] = *(const uint4_t*)src;
        } else if (idx < 896) {
            int z = idx - 784;
            int u = z >> 3, rem = z & 7;
            int w = 14 + (rem >> 2), d8 = (rem & 3) << 3;
            *(uint4_t*)&Klds[(u * 16 + w) * KP + d8] = (uint4_t){0, 0, 0, 0};
        }
    }
    #pragma unroll
    for (int rr = 0; rr < 2; ++rr) {
        int idx = tid + rr * 256;
        if (idx < 448) {
            int u = idx >> 5, rem = idx & 31;
            int pr = rem >> 2, d8 = (rem & 3) << 3;
            int kk0 = u * 16 + pr * 2;
            if (pr < 7) {
                const ushort_t* s0 = vp + ((size_t)((kr0 + u) * HH + kc0 + pr * 2)) * DD + d8;
                uint4_t a = *(const uint4_t*)s0;
                uint4_t c = *(const uint4_t*)(s0 + DD);
                #pragma unroll
                for (int e = 0; e < 4; ++e) {
                    unsigned lo = (a[e] & 0xFFFFu) | (c[e] << 16);
                    unsigned hi = (a[e] >> 16) | (c[e] & 0xFFFF0000u);
                    *(unsigned*)&Vlds[(d8 + 2 * e) * VPP + kk0] = lo;
                    *(unsigned*)&Vlds[(d8 + 2 * e + 1) * VPP + kk0] = hi;
                }
            } else {
                #pragma unroll
                for (int e = 0; e < 8; ++e)
                    *(unsigned*)&Vlds[(d8 + e) * VPP + kk0] = 0;
            }
        }
    }

    int lane = tid & 63, wv = tid >> 6;
    int l15 = lane & 15, quad = lane >> 4;
    int q_idx = wv * 16 + l15;
    int qi = i0 + (q_idx >> 3), qj = j0 + (q_idx & 7);
    int si = min(max(qi - 3, 0), HH - 7);
    int sj = min(max(qj - 3, 0), HH - 7);

    bf16x8 bq = *(const bf16x8*)(qp + ((size_t)(qi * HH + qj)) * DD + quad * 8);

    int jbase = kc0 + quad * 4 - sj;
    int cbase = kc0 + quad * 4 - qj + 6;
    int coff[4];
    bool cok[4];
    #pragma unroll
    for (int r2 = 0; r2 < 4; ++r2) {
        cok[r2] = (unsigned)(jbase + r2) <= 6u;
        coff[r2] = min(max(cbase + r2, 0), 12);
    }

    __syncthreads();

    f32x4 lg[KT];
    f32x4 zf = {0.f, 0.f, 0.f, 0.f};
    __builtin_amdgcn_s_setprio(1);             // T5: QK^T cluster
    #pragma unroll
    for (int t = 0; t < KT; ++t) {
        bf16x8 ak = *(const bf16x8*)&Klds[(t * 16 + l15) * KP + quad * 8];
        lg[t] = __builtin_amdgcn_mfma_f32_16x16x32_bf16(ak, bq, zf, 0, 0, 0);
    }
    __builtin_amdgcn_s_setprio(0);

    int abase = kr0 - qi + 6;
    #pragma unroll
    for (int t = 0; t < KT; ++t) {
        bool rok = (unsigned)(kr0 + t - si) <= 6u;
        int arow = min(max(abase + t, 0), 12);
        const float* br = &rpbl[arow * 13];
        #pragma unroll
        for (int r2 = 0; r2 < 4; ++r2) {
            float bias = br[coff[r2]];
            lg[t][r2] = (rok && cok[r2]) ? lg[t][r2] + bias : -1e30f;
        }
    }

    float m = -1e30f;
    #pragma unroll
    for (int t = 0; t < KT; ++t)
        #pragma unroll
        for (int r2 = 0; r2 < 4; ++r2) m = fmaxf(m, lg[t][r2]);
    m = fmaxf(m, __shfl_xor(m, 16));
    m = fmaxf(m, __shfl_xor(m, 32));
    float s = 0.f;
    #pragma unroll
    for (int t = 0; t < KT; ++t)
        #pragma unroll
        for (int r2 = 0; r2 < 4; ++r2) {
            float e = __expf(lg[t][r2] - m);
            lg[t][r2] = e;
            s += e;
        }
    s += __shfl_xor(s, 16);
    s += __shfl_xor(s, 32);
    float inv = 1.f / s;

    bf16x4 pb[KT];
    #pragma unroll
    for (int t = 0; t < KT; ++t) {
        union { uint2_t u; bf16x4 v; } cv;
        cv.u[0] = pack2(lg[t][0], lg[t][1]);
        cv.u[1] = pack2(lg[t][2], lg[t][3]);
        pb[t] = cv.v;
    }

    f32x4 acc0 = zf, acc1 = zf;
    __builtin_amdgcn_s_setprio(1);             // T5: PV cluster
    #pragma unroll
    for (int t = 0; t < KT; ++t) {
        bf16x4 bv0 = *(const bf16x4*)&Vlds[l15 * VPP + t * 16 + quad * 4];
        bf16x4 bv1 = *(const bf16x4*)&Vlds[(16 + l15) * VPP + t * 16 + quad * 4];
        acc0 = mfma16x16x16(pb[t], bv0, acc0);
        acc1 = mfma16x16x16(pb[t], bv1, acc1);
    }
    __builtin_amdgcn_s_setprio(0);

    ushort_t* op = qkv + (((size_t)b * HEADS + h) * HW) * DD;
    #pragma unroll
    for (int e = 0; e < 4; ++e) {
        float invq = __shfl(inv, quad * 4 + e);
        int q2 = wv * 16 + quad * 4 + e;
        int pix = (i0 + (q2 >> 3)) * HH + j0 + (q2 & 7);
        op[(size_t)pix * DD + l15] = f2bf(acc0[e] * invq);
        op[(size_t)pix * DD + 16 + l15] = f2bf(acc1[e] * invq);
    }
}

// ---------------- GEMM3 (bf16): y = attn_out . wpb^T + b; OUT f32 ----------------
// dbuf + T4 counted vmcnt(3), raw barriers; swizzled source + frag reads; XCD swizzle.
__global__ __launch_bounds__(256) void proj_gemm_bf16(const ushort_t* __restrict__ ao,
                                                      const ushort_t* __restrict__ w,
                                                      const float* __restrict__ bias,
                                                      float* __restrict__ out) {
    __shared__ __align__(16) ushort_t lds_p[2][64 * LPG];    // 2 x 4096 B
    __shared__ __align__(16) ushort_t lds_q[2][128 * LPG];   // 2 x 8192 B
    int tid = threadIdx.x;

    // T1 XCD swizzle: grid 49x4x8 = 1568 = 8 x 196; each XCD chunk = one batch b
    int lid = ((int)blockIdx.z * 4 + (int)blockIdx.y) * 49 + (int)blockIdx.x;
    int wl = (lid & 7) * 196 + (lid >> 3);
    int p0 = (wl % 49) * 64;
    int rest = wl / 49;
    int c0 = (rest % 4) * 128;
    int b = rest / 4;

    int lane = tid & 63, wv = tid >> 6;
    int wp = wv & 1, wq = wv >> 1;
    int quad = lane >> 4, l15 = lane & 15;

    f32x4 acc[2][4];
    #pragma unroll
    for (int i = 0; i < 2; ++i)
        #pragma unroll
        for (int jq = 0; jq < 4; ++jq) acc[i][jq] = (f32x4){0.f, 0.f, 0.f, 0.f};

    const ushort_t* abase = ao + ((size_t)b * HEADS) * HW * DD;
    int swz = (l15 >> 1) & 3;
    int cha = (quad ^ swz) * 8;

    int ca_row = tid >> 2;
    int ca_k8 = ((tid & 3) ^ ((tid >> 3) & 3)) * 8;
    int cb_row[2], cb_k8[2];
    #pragma unroll
    for (int r = 0; r < 2; ++r) {
        int c = r * 256 + tid;
        cb_row[r] = c >> 2;
        cb_k8[r] = ((c & 3) ^ ((c >> 3) & 3)) * 8;
    }

    auto compute_tile = [&](int cur) {
        bf16x8 afrag[2], bfrag[4];
        #pragma unroll
        for (int i = 0; i < 2; ++i)
            afrag[i] = *(const bf16x8*)&lds_p[cur][(wp * 32 + i * 16 + l15) * LPG + cha];
        #pragma unroll
        for (int jq = 0; jq < 4; ++jq)
            bfrag[jq] = *(const bf16x8*)&lds_q[cur][(wq * 64 + jq * 16 + l15) * LPG + cha];
        #pragma unroll
        for (int i = 0; i < 2; ++i)
            #pragma unroll
            for (int jq = 0; jq < 4; ++jq)
                acc[i][jq] = __builtin_amdgcn_mfma_f32_16x16x32_bf16(afrag[i], bfrag[jq],
                                                                     acc[i][jq], 0, 0, 0);
    };

    const int NKT = CC / 32;
    // prologue: stage tile 0 into buffer 0 (A k-tile 0 = head 0), full drain once
    gload16(abase + ((size_t)0 * HW + p0 + ca_row) * DD + ca_k8, &lds_p[0][tid * 8]);
    #pragma unroll
    for (int r = 0; r < 2; ++r)
        gload16(w + (size_t)(c0 + cb_row[r]) * CC + cb_k8[r],
                &lds_q[0][(r * 256 + tid) * 8]);
    asm volatile("s_waitcnt vmcnt(0)" ::: "memory");
    __builtin_amdgcn_s_barrier();
    asm volatile("" ::: "memory");

    for (int kt = 0; kt < NKT - 1; ++kt) {
        int cur = kt & 1;
        int kn = kt + 1;
        gload16(abase + ((size_t)kn * HW + p0 + ca_row) * DD + ca_k8,
                &lds_p[cur ^ 1][tid * 8]);
        #pragma unroll
        for (int r = 0; r < 2; ++r)
            gload16(w + (size_t)(c0 + cb_row[r]) * CC + kn * 32 + cb_k8[r],
                    &lds_q[cur ^ 1][(r * 256 + tid) * 8]);
        // T4: wait ONLY for tile kt's 3 loads; kt+1's 3 stay in flight
        asm volatile("s_waitcnt vmcnt(3)" ::: "memory");
        __builtin_amdgcn_s_barrier();
        asm volatile("" ::: "memory");
        compute_tile(cur);
        asm volatile("" ::: "memory");
        __builtin_amdgcn_s_barrier();
        asm volatile("" ::: "memory");
    }
    asm volatile("s_waitcnt vmcnt(0)" ::: "memory");
    __builtin_amdgcn_s_barrier();
    asm volatile("" ::: "memory");
    compute_tile((NKT - 1) & 1);

    #pragma unroll
    for (int i = 0; i < 2; ++i) {
        int pix = p0 + wp * 32 + i * 16 + quad * 4;
        #pragma unroll
        for (int jq = 0; jq < 4; ++jq) {
            int cch = c0 + wq * 64 + jq * 16 + l15;
            float bz = bias[cch];
            float4 v;
            v.x = acc[i][jq][0] + bz;
            v.y = acc[i][jq][1] + bz;
            v.z = acc[i][jq][2] + bz;
            v.w = acc[i][jq][3] + bz;
            float* dst = out + ((size_t)b * CC + cch) * HW + pix;
            *(float4*)dst = v;
        }
    }
}

// ---------------- GEMM3 fallback (f32 w) ----------------
__global__ __launch_bounds__(256) void proj_gemm_kernel(const ushort_t* __restrict__ ao,
                                                        const float* __restrict__ w,
                                                        const float* __restrict__ bias,
                                                        float* __restrict__ out) {
    __shared__ __align__(16) ushort_t lds_p[64 * LP];
    __shared__ __align__(16) ushort_t lds_q[128 * LP];
    const int K = CC;
    int tid = threadIdx.x;
    int b = blockIdx.z;
    int p0 = blockIdx.x * 64;
    int c0 = blockIdx.y * 128;
    int lane = tid & 63, wv = tid >> 6;
    int wp = wv & 1, wq = wv >> 1;
    int quad = lane >> 4, l15 = lane & 15;

    f32x4 acc[2][4];
    #pragma unroll
    for (int i = 0; i < 2; ++i)
        #pragma unroll
        for (int jq = 0; jq < 4; ++jq) acc[i][jq] = (f32x4){0.f, 0.f, 0.f, 0.f};

    const ushort_t* abase = ao + ((size_t)b * HEADS) * HW * DD;

    for (int kt = 0; kt < K / 32; ++kt) {
        __syncthreads();
        {
            int row = tid >> 2, k8 = (tid & 3) * 8;
            uint4_t u = *(const uint4_t*)(abase + ((size_t)kt * HW + p0 + row) * DD + k8);
            *(uint4_t*)&lds_p[row * LP + k8] = u;
        }
        #pragma unroll
        for (int r = 0; r < 2; ++r) {
            int chunk = tid + r * 256;
            int row = chunk >> 2, k8 = (chunk & 3) * 8;
            const float* src = w + (size_t)(c0 + row) * K + kt * 32 + k8;
            float4 f0 = *(const float4*)src;
            float4 f1 = *(const float4*)(src + 4);
            uint4_t u;
            u[0] = pack2(f0.x, f0.y);
            u[1] = pack2(f0.z, f0.w);
            u[2] = pack2(f1.x, f1.y);
            u[3] = pack2(f1.z, f1.w);
            *(uint4_t*)&lds_q[row * LP + k8] = u;
        }
        __syncthreads();
        bf16x8 afrag[2], bfrag[4];
        #pragma unroll
        for (int i = 0; i < 2; ++i)
            afrag[i] = *(const bf16x8*)&lds_p[(wp * 32 + i * 16 + l15) * LP + quad * 8];
        #pragma unroll
        for (int jq = 0; jq < 4; ++jq)
            bfrag[jq] = *(const bf16x8*)&lds_q[(wq * 64 + jq * 16 + l15) * LP + quad * 8];
        #pragma unroll
        for (int i = 0; i < 2; ++i)
            #pragma unroll
            for (int jq = 0; jq < 4; ++jq)
                acc[i][jq] = __builtin_amdgcn_mfma_f32_16x16x32_bf16(afrag[i], bfrag[jq],
                                                                     acc[i][jq], 0, 0, 0);
    }
    #pragma unroll
    for (int i = 0; i < 2; ++i) {
        int pix = p0 + wp * 32 + i * 16 + quad * 4;
        #pragma unroll
        for (int jq = 0; jq < 4; ++jq) {
            int cch = c0 + wq * 64 + jq * 16 + l15;
            float bz = bias[cch];
            float4 v;
            v.x = acc[i][jq][0] + bz;
            v.y = acc[i][jq][1] + bz;
            v.z = acc[i][jq][2] + bz;
            v.w = acc[i][jq][3] + bz;
            float* dst = out + ((size_t)b * CC + cch) * HW + pix;
            *(float4*)dst = v;
        }
    }
}

extern "C" void kernel_launch(void* const* d_in, const int* in_sizes, int n_in,
                              void* d_out, int out_size, void* d_ws, size_t ws_size,
                              hipStream_t stream) {
    const float* x = (const float*)d_in[0];
    const float* qkv_w = (const float*)d_in[1];
    const float* rpb = (const float*)d_in[2];
    const float* proj_w = (const float*)d_in[3];
    const float* proj_b = (const float*)d_in[4];
    float* out = (float*)d_out;

    size_t need_min = 3 * PLANE * sizeof(ushort_t);                       // 73.5 MB
    size_t need_full = (4 * PLANE + WQ_ELEMS + WP_ELEMS) * sizeof(ushort_t);  // 100 MB

    if (ws_size < need_min) {
        zero_out_f32<<<dim3((int)((OUT_TOT + 255) / 256)), dim3(256), 0, stream>>>(out);
        return;
    }

    ushort_t* qkv = (ushort_t*)d_ws;                 // q/k/v: 3 bf16 planes

    if (ws_size >= need_full) {
        ushort_t* xbf = qkv + 3 * PLANE;             // bf16 x, [b][hw][c] (TRANSPOSED)
        ushort_t* wqb = qkv + 4 * PLANE;             // bf16 qkv_w
        ushort_t* wpb = wqb + WQ_ELEMS;              // bf16 proj_w

        xpose_cvt<<<dim3(49, 8, 8), dim3(256), 0, stream>>>(x, xbf);
        cvt_weights<<<dim3((WQ_ELEMS / 8 + WP_ELEMS / 8 + 255) / 256), dim3(256), 0,
                      stream>>>(qkv_w, wqb, WQ_ELEMS / 8, proj_w, wpb, WP_ELEMS / 8);

        qkv_gemm_bf16<<<dim3(49, 6, 8), dim3(128), 0, stream>>>(xbf, wqb, qkv);
        attn_mfma<<<dim3(49, HEADS, BATCH), dim3(256), 0, stream>>>(qkv, rpb);
        proj_gemm_bf16<<<dim3(49, 4, 8), dim3(256), 0, stream>>>(qkv, wpb, proj_b, out);
    } else {
        qkv_gemm_kernel<<<dim3(49, 12, 8), dim3(256), 0, stream>>>(x, qkv_w, qkv);
        attn_mfma<<<dim3(49, HEADS, BATCH), dim3(256), 0, stream>>>(qkv, rpb);
        proj_gemm_kernel<<<dim3(49, 4, 8), dim3(256), 0, stream>>>(qkv, proj_w, proj_b, out);
    }
}

// Round 14
// 255.255 us; speedup vs baseline: 1.1128x; 1.1128x over previous
//
#include <hip/hip_runtime.h>

// NeighborhoodAttention2D: B=8, C=512, H=W=56, heads=16, d=32, KSZ=7
// Round 22: REVERT r21's 2-wave qkv (110us: Occ 10%, VALU 36% — intensity
// theory refuted). Back to green r20 4-wave structure, with ONE change:
// TRI-BUFFER the qkv pipeline (depth-2 prefetch).
//  Mechanism: r20's dbuf covers tile-t loads by ~1 iter (~364cyc) — enough for
//  L2 (~200cyc) but not first-touch HBM misses (~900cyc, m126). Depth-2 gives
//  ~730cyc cover. LDS 40.9->61.4KB; measured residency was already ~2 blk/CU.
//  In-loop waits vmcnt(10), tail vmcnt(5)/vmcnt(0) (in-order retire).
//  Race audit: buf(t+2)%3's last readers = iter t-1, fenced by its end barrier.
// attn/proj/prep/fallbacks byte-identical to green r20.

typedef unsigned short ushort_t;
typedef short bf16x8 __attribute__((ext_vector_type(8)));      // 8 bf16 = 4 VGPRs
typedef short bf16x4 __attribute__((ext_vector_type(4)));      // 4 bf16 = 2 VGPRs
typedef float f32x4 __attribute__((ext_vector_type(4)));       // MFMA C/D frag
typedef unsigned int uint4_t __attribute__((ext_vector_type(4)));
typedef unsigned int uint2_t __attribute__((ext_vector_type(2)));

#define BATCH 8
#define HEADS 16
#define HW 3136
#define HH 56
#define DD 32
#define CC 512
#define PLANE ((size_t)BATCH * HEADS * HW * DD)   // 12,845,056 elems (= B*C*HW)
#define OUT_TOT ((size_t)BATCH * CC * HW)
#define LP 40                                      // fallback-GEMM LDS pitch
#define LPG 32                                     // gload_lds GEMM pitch (linear rows)

// attention tile geometry
#define KT 14
#define KP 32
#define VPP 228

#define WQ_ELEMS (1536 * 512)
#define WP_ELEMS (512 * 512)

__device__ __forceinline__ ushort_t f2bf(float f) {
    union { float f; unsigned int i; } v; v.f = f;
    unsigned int r = v.i + 0x7FFFu + ((v.i >> 16) & 1u);   // RNE
    return (ushort_t)(r >> 16);
}
__device__ __forceinline__ unsigned int pack2(float a, float b) {
    return (unsigned int)f2bf(a) | ((unsigned int)f2bf(b) << 16);
}

__device__ __forceinline__ f32x4 mfma16x16x16(bf16x4 a, bf16x4 b, f32x4 c) {
#if __has_builtin(__builtin_amdgcn_mfma_f32_16x16x16bf16_1k)
    return __builtin_amdgcn_mfma_f32_16x16x16bf16_1k(a, b, c, 0, 0, 0);
#else
    f32x4 d;
    asm("v_mfma_f32_16x16x16_bf16 %0, %1, %2, %3" : "=v"(d) : "v"(a), "v"(b), "v"(c));
    return d;
#endif
}

// async global->LDS, 16B per lane; lds dest must be wave-linear (base + lane*16)
__device__ __forceinline__ void gload16(const ushort_t* g, ushort_t* l) {
    __builtin_amdgcn_global_load_lds(
        (const __attribute__((address_space(1))) unsigned int*)g,
        (__attribute__((address_space(3))) unsigned int*)l, 16, 0, 0);
}

__global__ __launch_bounds__(256) void zero_out_f32(float* __restrict__ out) {
    size_t idx = (size_t)blockIdx.x * 256 + threadIdx.x;
    if (idx < OUT_TOT) out[idx] = 0.f;
}

// ---------------- prep: both weight matrices f32 -> bf16, one launch ----------------
__global__ __launch_bounds__(256) void cvt_weights(const float* __restrict__ wa,
                                                   ushort_t* __restrict__ da, int n8a,
                                                   const float* __restrict__ wb,
                                                   ushort_t* __restrict__ db, int n8b) {
    int idx = blockIdx.x * 256 + threadIdx.x;
    const float* s;
    ushort_t* d;
    int i;
    if (idx < n8a) {
        s = wa; d = da; i = idx;
    } else {
        i = idx - n8a;
        if (i >= n8b) return;
        s = wb; d = db;
    }
    const float4* sp = (const float4*)s + (size_t)i * 2;
    float4 f0 = sp[0], f1 = sp[1];
    uint4_t u;
    u[0] = pack2(f0.x, f0.y);
    u[1] = pack2(f0.z, f0.w);
    u[2] = pack2(f1.x, f1.y);
    u[3] = pack2(f1.z, f1.w);
    *(uint4_t*)(d + (size_t)i * 8) = u;
}

// ---------------- prep: x [b][c][hw] f32 -> xbf [b][hw][c] bf16 ----------------
__global__ __launch_bounds__(256) void xpose_cvt(const float* __restrict__ x,
                                                 ushort_t* __restrict__ xb) {
    __shared__ ushort_t T[64 * 64];                // 8192 B
    int tid = threadIdx.x;
    int hw0 = blockIdx.x * 64;
    int c0 = blockIdx.y * 64;
    int b = blockIdx.z;

    int cr = tid >> 2, hq = tid & 3;
    const float* src = x + ((size_t)b * CC + c0 + cr) * HW + hw0 + hq * 16;
    float4 f0 = *(const float4*)(src);
    float4 f1 = *(const float4*)(src + 4);
    float4 f2 = *(const float4*)(src + 8);
    float4 f3 = *(const float4*)(src + 12);
    uint4_t u0, u1;
    u0[0] = pack2(f0.x, f0.y); u0[1] = pack2(f0.z, f0.w);
    u0[2] = pack2(f1.x, f1.y); u0[3] = pack2(f1.z, f1.w);
    u1[0] = pack2(f2.x, f2.y); u1[1] = pack2(f2.z, f2.w);
    u1[2] = pack2(f3.x, f3.y); u1[3] = pack2(f3.z, f3.w);
    int sw = ((cr >> 4) & 3) << 4;
    int col0 = (hq * 16) ^ sw;
    *(uint4_t*)&T[cr * 64 + col0] = u0;
    *(uint4_t*)&T[cr * 64 + col0 + 8] = u1;

    __syncthreads();

    int p = tid >> 2, cq = tid & 3;
    int pc = p ^ (cq << 4);
    unsigned vv[8];
    #pragma unroll
    for (int j = 0; j < 16; j += 2) {
        unsigned a = T[(cq * 16 + j) * 64 + pc];
        unsigned b2 = T[(cq * 16 + j + 1) * 64 + pc];
        vv[j >> 1] = a | (b2 << 16);
    }
    ushort_t* dst = xb + ((size_t)b * HW + hw0 + p) * CC + c0 + cq * 16;
    uint4_t w0, w1;
    w0[0] = vv[0]; w0[1] = vv[1]; w0[2] = vv[2]; w0[3] = vv[3];
    w1[0] = vv[4]; w1[1] = vv[5]; w1[2] = vv[6]; w1[3] = vv[7];
    *(uint4_t*)&dst[0] = w0;
    *(uint4_t*)&dst[8] = w1;
}

// ---------------- GEMM1 (bf16): qkv^T = wq (1536x512) . xb ([b][hw][c]) ----------
// 256n x 64px tile, TRI-buffer + counted vmcnt(10/5/0), raw barriers, XCD swizzle.
__global__ __launch_bounds__(256) void qkv_gemm_bf16(const ushort_t* __restrict__ xb,
                                                     const ushort_t* __restrict__ w,
                                                     ushort_t* __restrict__ qkv) {
    __shared__ __align__(16) ushort_t lds_p[3][256 * LPG];   // 3 x 16384 B
    __shared__ __align__(16) ushort_t lds_q[3][64 * LPG];    // 3 x  4096 B
    int tid = threadIdx.x;

    // T1 XCD swizzle: grid 49x6x8 = 2352 = 8 x 294; each XCD chunk = one batch b
    int lid = ((int)blockIdx.z * 6 + (int)blockIdx.y) * 49 + (int)blockIdx.x;
    int wl = (lid & 7) * 294 + (lid >> 3);
    int p0 = (wl % 49) * 64;
    int rest = wl / 49;
    int n0 = (rest % 6) * 256;
    int b = rest / 6;

    int lane = tid & 63, wv = tid >> 6;
    int wp = wv & 1, wq = wv >> 1;
    int quad = lane >> 4, l15 = lane & 15;

    f32x4 acc[8][2];
    #pragma unroll
    for (int i = 0; i < 8; ++i)
        #pragma unroll
        for (int jq = 0; jq < 2; ++jq) acc[i][jq] = (f32x4){0.f, 0.f, 0.f, 0.f};

    int swz = (l15 >> 1) & 3;                  // fragment-read swizzle (row->chunk)
    int cha = (quad ^ swz) * 8;                // swizzled k-octet for frag reads

    // per-thread staging descriptors (constant across kt)
    int ca_row[4], ca_k8[4];
    #pragma unroll
    for (int r = 0; r < 4; ++r) {
        int c = r * 256 + tid;
        ca_row[r] = c >> 2;
        ca_k8[r] = ((c & 3) ^ ((c >> 3) & 3)) * 8;
    }
    int cb_row = tid >> 2;
    int cb_k8 = ((tid & 3) ^ ((tid >> 3) & 3)) * 8;

    auto stage = [&](int buf, int ko) {
        #pragma unroll
        for (int r = 0; r < 4; ++r)
            gload16(w + (size_t)(n0 + ca_row[r]) * CC + ko + ca_k8[r],
                    &lds_p[buf][(r * 256 + tid) * 8]);
        gload16(xb + ((size_t)b * HW + p0 + cb_row) * CC + ko + cb_k8,
                &lds_q[buf][tid * 8]);
    };

    auto compute_tile = [&](int cur) {
        bf16x8 afrag[8], bfrag[2];
        #pragma unroll
        for (int i = 0; i < 8; ++i)
            afrag[i] = *(const bf16x8*)&lds_p[cur][(wp * 128 + i * 16 + l15) * LPG + cha];
        #pragma unroll
        for (int jq = 0; jq < 2; ++jq)
            bfrag[jq] = *(const bf16x8*)&lds_q[cur][(wq * 32 + jq * 16 + l15) * LPG + cha];
        #pragma unroll
        for (int i = 0; i < 8; ++i)
            #pragma unroll
            for (int jq = 0; jq < 2; ++jq)
                acc[i][jq] = __builtin_amdgcn_mfma_f32_16x16x32_bf16(afrag[i], bfrag[jq],
                                                                     acc[i][jq], 0, 0, 0);
    };

    const int NKT = CC / 32;                   // 16
    // prologue: stage tiles 0 and 1 (depth-2); loop's wait+barrier covers tile 0
    stage(0, 0);
    stage(1, 32);

    for (int t = 0; t < NKT; ++t) {
        int cur = t % 3;
        if (t + 2 < NKT) stage((t + 2) % 3, (t + 2) * 32);
        // counted wait for tile t's 5 loads (oldest); later tiles stay in flight
        if (t < NKT - 2)
            asm volatile("s_waitcnt vmcnt(10)" ::: "memory");
        else if (t == NKT - 2)
            asm volatile("s_waitcnt vmcnt(5)" ::: "memory");
        else
            asm volatile("s_waitcnt vmcnt(0)" ::: "memory");
        __builtin_amdgcn_s_barrier();
        asm volatile("" ::: "memory");
        compute_tile(cur);
        asm volatile("" ::: "memory");
        __builtin_amdgcn_s_barrier();          // readers of buf(t%3) done before its re-stage
        asm volatile("" ::: "memory");
    }

    const float qscale = 0.17677669529663687f;   // 1/sqrt(32)
    #pragma unroll
    for (int i = 0; i < 8; ++i) {
        int nbase = n0 + wp * 128 + i * 16 + quad * 4;
        int which = nbase >> 9;
        int h = (nbase >> 5) & 15;
        int dch = nbase & 31;
        float sc = (which == 0) ? qscale : 1.0f;
        #pragma unroll
        for (int jq = 0; jq < 2; ++jq) {
            int pix = p0 + wq * 32 + jq * 16 + l15;
            uint2_t v;
            v[0] = pack2(acc[i][jq][0] * sc, acc[i][jq][1] * sc);
            v[1] = pack2(acc[i][jq][2] * sc, acc[i][jq][3] * sc);
            ushort_t* dst = qkv + (size_t)which * PLANE +
                            ((((size_t)b * HEADS + h) * HW + pix) * DD + dch);
            *(uint2_t*)dst = v;
        }
    }
}

// ---------------- GEMM1 fallback (f32 inputs) ----------------
__global__ __launch_bounds__(256) void qkv_gemm_kernel(const float* __restrict__ x,
                                                       const float* __restrict__ w,
                                                       ushort_t* __restrict__ qkv) {
    __shared__ __align__(16) ushort_t lds_p[128 * LP];
    __shared__ __align__(16) ushort_t lds_q[64 * LP];
    const int K = CC;
    int tid = threadIdx.x;
    int b = blockIdx.z;
    int n0 = blockIdx.y * 128;
    int p0 = blockIdx.x * 64;
    int lane = tid & 63, wv = tid >> 6;
    int wp = wv & 1, wq = wv >> 1;
    int quad = lane >> 4, l15 = lane & 15;

    f32x4 acc[4][2];
    #pragma unroll
    for (int i = 0; i < 4; ++i)
        #pragma unroll
        for (int jq = 0; jq < 2; ++jq) acc[i][jq] = (f32x4){0.f, 0.f, 0.f, 0.f};

    int spx = tid & 63;
    int sk8 = (tid >> 6) * 8;

    for (int kt = 0; kt < K / 32; ++kt) {
        __syncthreads();
        #pragma unroll
        for (int r = 0; r < 2; ++r) {
            int chunk = tid + r * 256;
            int row = chunk >> 2, k8 = (chunk & 3) * 8;
            const float* src = w + (size_t)(n0 + row) * K + kt * 32 + k8;
            float4 f0 = *(const float4*)src;
            float4 f1 = *(const float4*)(src + 4);
            uint4_t u;
            u[0] = pack2(f0.x, f0.y);
            u[1] = pack2(f0.z, f0.w);
            u[2] = pack2(f1.x, f1.y);
            u[3] = pack2(f1.z, f1.w);
            *(uint4_t*)&lds_p[row * LP + k8] = u;
        }
        {
            const float* xcol = x + ((size_t)b * CC + kt * 32 + sk8) * HW + p0 + spx;
            float v0 = xcol[0];
            float v1 = xcol[(size_t)HW];
            float v2 = xcol[(size_t)2 * HW];
            float v3 = xcol[(size_t)3 * HW];
            float v4 = xcol[(size_t)4 * HW];
            float v5 = xcol[(size_t)5 * HW];
            float v6 = xcol[(size_t)6 * HW];
            float v7 = xcol[(size_t)7 * HW];
            uint4_t u;
            u[0] = pack2(v0, v1);
            u[1] = pack2(v2, v3);
            u[2] = pack2(v4, v5);
            u[3] = pack2(v6, v7);
            *(uint4_t*)&lds_q[spx * LP + sk8] = u;
        }
        __syncthreads();
        bf16x8 afrag[4], bfrag[2];
        #pragma unroll
        for (int i = 0; i < 4; ++i)
            afrag[i] = *(const bf16x8*)&lds_p[(wp * 64 + i * 16 + l15) * LP + quad * 8];
        #pragma unroll
        for (int jq = 0; jq < 2; ++jq)
            bfrag[jq] = *(const bf16x8*)&lds_q[(wq * 32 + jq * 16 + l15) * LP + quad * 8];
        #pragma unroll
        for (int i = 0; i < 4; ++i)
            #pragma unroll
            for (int jq = 0; jq < 2; ++jq)
                acc[i][jq] = __builtin_amdgcn_mfma_f32_16x16x32_bf16(afrag[i], bfrag[jq],
                                                                     acc[i][jq], 0, 0, 0);
    }
    const float qscale = 0.17677669529663687f;
    #pragma unroll
    for (int i = 0; i < 4; ++i) {
        int nbase = n0 + wp * 64 + i * 16 + quad * 4;
        int which = nbase >> 9;
        int h = (nbase >> 5) & 15;
        int dch = nbase & 31;
        float sc = (which == 0) ? qscale : 1.0f;
        #pragma unroll
        for (int jq = 0; jq < 2; ++jq) {
            int pix = p0 + wq * 32 + jq * 16 + l15;
            uint2_t v;
            v[0] = pack2(acc[i][jq][0] * sc, acc[i][jq][1] * sc);
            v[1] = pack2(acc[i][jq][2] * sc, acc[i][jq][3] * sc);
            ushort_t* dst = qkv + (size_t)which * PLANE +
                            ((((size_t)b * HEADS + h) * HW + pix) * DD + dch);
            *(uint2_t*)dst = v;
        }
    }
}

// ---------------- MFMA attention: one block per (b, h, 8x8 query tile) ----------------
__global__ __launch_bounds__(256, 4) void attn_mfma(ushort_t* __restrict__ qkv,
                                                    const float* __restrict__ rpb) {
    __shared__ __align__(16) ushort_t Klds[224 * KP];        // 14336 B, [kk][d]
    __shared__ __align__(16) ushort_t Vlds[DD * VPP];        // 14592 B, [d][kk]
    __shared__ float rpbl[169];                              //   676 B

    int tid = threadIdx.x;

    // T1 XCD swizzle: grid 49x16x8 = 6272 = 8 x 784; each XCD chunk = one batch b
    int lid = ((int)blockIdx.z * 16 + (int)blockIdx.y) * 49 + (int)blockIdx.x;
    int wl = (lid & 7) * 784 + (lid >> 3);
    int tile = wl % 49;
    int rest = wl / 49;
    int h = rest % 16;
    int b = rest / 16;

    int ti = tile / 7, tj = tile - ti * 7;
    int i0 = ti * 8, j0 = tj * 8;
    int kr0 = min(max(i0 - 3, 0), HH - 14);
    int kc0 = min(max(j0 - 3, 0), HH - 14);

    const ushort_t* qp = qkv + (((size_t)b * HEADS + h) * HW) * DD;
    const ushort_t* kp = qp + PLANE;
    const ushort_t* vp = qp + 2 * PLANE;

    if (tid < 169) rpbl[tid] = rpb[h * 169 + tid];

    #pragma unroll
    for (int r = 0; r < 4; ++r) {
        int idx = tid + r * 256;
        if (idx < 784) {
            int u = idx / 56;
            int rem = idx - u * 56;
            int w = rem >> 2, d8 = (rem & 3) << 3;
            const ushort_t* src = kp + ((size_t)((kr0 + u) * HH + kc0 + w)) * DD + d8;
            *(uint4_t*)&Klds[(u * 16 + w) * KP + d8] = *(const uint4_t*)src;
        } else if (idx < 896) {
            int z = idx - 784;
            int u = z >> 3, rem = z & 7;
            int w = 14 + (rem >> 2), d8 = (rem & 3) << 3;
            *(uint4_t*)&Klds[(u * 16 + w) * KP + d8] = (uint4_t){0, 0, 0, 0};
        }
    }
    #pragma unroll
    for (int rr = 0; rr < 2; ++rr) {
        int idx = tid + rr * 256;
        if (idx < 448) {
            int u = idx >> 5, rem = idx & 31;
            int pr = rem >> 2, d8 = (rem & 3) << 3;
            int kk0 = u * 16 + pr * 2;
            if (pr < 7) {
                const ushort_t* s0 = vp + ((size_t)((kr0 + u) * HH + kc0 + pr * 2)) * DD + d8;
                uint4_t a = *(const uint4_t*)s0;
                uint4_t c = *(const uint4_t*)(s0 + DD);
                #pragma unroll
                for (int e = 0; e < 4; ++e) {
                    unsigned lo = (a[e] & 0xFFFFu) | (c[e] << 16);
                    unsigned hi = (a[e] >> 16) | (c[e] & 0xFFFF0000u);
                    *(unsigned*)&Vlds[(d8 + 2 * e) * VPP + kk0] = lo;
                    *(unsigned*)&Vlds[(d8 + 2 * e + 1) * VPP + kk0] = hi;
                }
            } else {
                #pragma unroll
                for (int e = 0; e < 8; ++e)
                    *(unsigned*)&Vlds[(d8 + e) * VPP + kk0] = 0;
            }
        }
    }

    int lane = tid & 63, wv = tid >> 6;
    int l15 = lane & 15, quad = lane >> 4;
    int q_idx = wv * 16 + l15;
    int qi = i0 + (q_idx >> 3), qj = j0 + (q_idx & 7);
    int si = min(max(qi - 3, 0), HH - 7);
    int sj = min(max(qj - 3, 0), HH - 7);

    bf16x8 bq = *(const bf16x8*)(qp + ((size_t)(qi * HH + qj)) * DD + quad * 8);

    int jbase = kc0 + quad * 4 - sj;
    int cbase = kc0 + quad * 4 - qj + 6;
    int coff[4];
    bool cok[4];
    #pragma unroll
    for (int r2 = 0; r2 < 4; ++r2) {
        cok[r2] = (unsigned)(jbase + r2) <= 6u;
        coff[r2] = min(max(cbase + r2, 0), 12);
    }

    __syncthreads();

    f32x4 lg[KT];
    f32x4 zf = {0.f, 0.f, 0.f, 0.f};
    __builtin_amdgcn_s_setprio(1);             // T5: QK^T cluster
    #pragma unroll
    for (int t = 0; t < KT; ++t) {
        bf16x8 ak = *(const bf16x8*)&Klds[(t * 16 + l15) * KP + quad * 8];
        lg[t] = __builtin_amdgcn_mfma_f32_16x16x32_bf16(ak, bq, zf, 0, 0, 0);
    }
    __builtin_amdgcn_s_setprio(0);

    int abase = kr0 - qi + 6;
    #pragma unroll
    for (int t = 0; t < KT; ++t) {
        bool rok = (unsigned)(kr0 + t - si) <= 6u;
        int arow = min(max(abase + t, 0), 12);
        const float* br = &rpbl[arow * 13];
        #pragma unroll
        for (int r2 = 0; r2 < 4; ++r2) {
            float bias = br[coff[r2]];
            lg[t][r2] = (rok && cok[r2]) ? lg[t][r2] + bias : -1e30f;
        }
    }

    float m = -1e30f;
    #pragma unroll
    for (int t = 0; t < KT; ++t)
        #pragma unroll
        for (int r2 = 0; r2 < 4; ++r2) m = fmaxf(m, lg[t][r2]);
    m = fmaxf(m, __shfl_xor(m, 16));
    m = fmaxf(m, __shfl_xor(m, 32));
    float s = 0.f;
    #pragma unroll
    for (int t = 0; t < KT; ++t)
        #pragma unroll
        for (int r2 = 0; r2 < 4; ++r2) {
            float e = __expf(lg[t][r2] - m);
            lg[t][r2] = e;
            s += e;
        }
    s += __shfl_xor(s, 16);
    s += __shfl_xor(s, 32);
    float inv = 1.f / s;

    bf16x4 pb[KT];
    #pragma unroll
    for (int t = 0; t < KT; ++t) {
        union { uint2_t u; bf16x4 v; } cv;
        cv.u[0] = pack2(lg[t][0], lg[t][1]);
        cv.u[1] = pack2(lg[t][2], lg[t][3]);
        pb[t] = cv.v;
    }

    f32x4 acc0 = zf, acc1 = zf;
    __builtin_amdgcn_s_setprio(1);             // T5: PV cluster
    #pragma unroll
    for (int t = 0; t < KT; ++t) {
        bf16x4 bv0 = *(const bf16x4*)&Vlds[l15 * VPP + t * 16 + quad * 4];
        bf16x4 bv1 = *(const bf16x4*)&Vlds[(16 + l15) * VPP + t * 16 + quad * 4];
        acc0 = mfma16x16x16(pb[t], bv0, acc0);
        acc1 = mfma16x16x16(pb[t], bv1, acc1);
    }
    __builtin_amdgcn_s_setprio(0);

    ushort_t* op = qkv + (((size_t)b * HEADS + h) * HW) * DD;
    #pragma unroll
    for (int e = 0; e < 4; ++e) {
        float invq = __shfl(inv, quad * 4 + e);
        int q2 = wv * 16 + quad * 4 + e;
        int pix = (i0 + (q2 >> 3)) * HH + j0 + (q2 & 7);
        op[(size_t)pix * DD + l15] = f2bf(acc0[e] * invq);
        op[(size_t)pix * DD + 16 + l15] = f2bf(acc1[e] * invq);
    }
}

// ---------------- GEMM3 (bf16): y = attn_out . wpb^T + b; OUT f32 ----------------
// dbuf + T4 counted vmcnt(3), raw barriers; swizzled source + frag reads; XCD swizzle.
__global__ __launch_bounds__(256) void proj_gemm_bf16(const ushort_t* __restrict__ ao,
                                                      const ushort_t* __restrict__ w,
                                                      const float* __restrict__ bias,
                                                      float* __restrict__ out) {
    __shared__ __align__(16) ushort_t lds_p[2][64 * LPG];    // 2 x 4096 B
    __shared__ __align__(16) ushort_t lds_q[2][128 * LPG];   // 2 x 8192 B
    int tid = threadIdx.x;

    // T1 XCD swizzle: grid 49x4x8 = 1568 = 8 x 196; each XCD chunk = one batch b
    int lid = ((int)blockIdx.z * 4 + (int)blockIdx.y) * 49 + (int)blockIdx.x;
    int wl = (lid & 7) * 196 + (lid >> 3);
    int p0 = (wl % 49) * 64;
    int rest = wl / 49;
    int c0 = (rest % 4) * 128;
    int b = rest / 4;

    int lane = tid & 63, wv = tid >> 6;
    int wp = wv & 1, wq = wv >> 1;
    int quad = lane >> 4, l15 = lane & 15;

    f32x4 acc[2][4];
    #pragma unroll
    for (int i = 0; i < 2; ++i)
        #pragma unroll
        for (int jq = 0; jq < 4; ++jq) acc[i][jq] = (f32x4){0.f, 0.f, 0.f, 0.f};

    const ushort_t* abase = ao + ((size_t)b * HEADS) * HW * DD;
    int swz = (l15 >> 1) & 3;
    int cha = (quad ^ swz) * 8;

    int ca_row = tid >> 2;
    int ca_k8 = ((tid & 3) ^ ((tid >> 3) & 3)) * 8;
    int cb_row[2], cb_k8[2];
    #pragma unroll
    for (int r = 0; r < 2; ++r) {
        int c = r * 256 + tid;
        cb_row[r] = c >> 2;
        cb_k8[r] = ((c & 3) ^ ((c >> 3) & 3)) * 8;
    }

    auto compute_tile = [&](int cur) {
        bf16x8 afrag[2], bfrag[4];
        #pragma unroll
        for (int i = 0; i < 2; ++i)
            afrag[i] = *(const bf16x8*)&lds_p[cur][(wp * 32 + i * 16 + l15) * LPG + cha];
        #pragma unroll
        for (int jq = 0; jq < 4; ++jq)
            bfrag[jq] = *(const bf16x8*)&lds_q[cur][(wq * 64 + jq * 16 + l15) * LPG + cha];
        #pragma unroll
        for (int i = 0; i < 2; ++i)
            #pragma unroll
            for (int jq = 0; jq < 4; ++jq)
                acc[i][jq] = __builtin_amdgcn_mfma_f32_16x16x32_bf16(afrag[i], bfrag[jq],
                                                                     acc[i][jq], 0, 0, 0);
    };

    const int NKT = CC / 32;
    // prologue: stage tile 0 into buffer 0 (A k-tile 0 = head 0), full drain once
    gload16(abase + ((size_t)0 * HW + p0 + ca_row) * DD + ca_k8, &lds_p[0][tid * 8]);
    #pragma unroll
    for (int r = 0; r < 2; ++r)
        gload16(w + (size_t)(c0 + cb_row[r]) * CC + cb_k8[r],
                &lds_q[0][(r * 256 + tid) * 8]);
    asm volatile("s_waitcnt vmcnt(0)" ::: "memory");
    __builtin_amdgcn_s_barrier();
    asm volatile("" ::: "memory");

    for (int kt = 0; kt < NKT - 1; ++kt) {
        int cur = kt & 1;
        int kn = kt + 1;
        gload16(abase + ((size_t)kn * HW + p0 + ca_row) * DD + ca_k8,
                &lds_p[cur ^ 1][tid * 8]);
        #pragma unroll
        for (int r = 0; r < 2; ++r)
            gload16(w + (size_t)(c0 + cb_row[r]) * CC + kn * 32 + cb_k8[r],
                    &lds_q[cur ^ 1][(r * 256 + tid) * 8]);
        // T4: wait ONLY for tile kt's 3 loads; kt+1's 3 stay in flight
        asm volatile("s_waitcnt vmcnt(3)" ::: "memory");
        __builtin_amdgcn_s_barrier();
        asm volatile("" ::: "memory");
        compute_tile(cur);
        asm volatile("" ::: "memory");
        __builtin_amdgcn_s_barrier();
        asm volatile("" ::: "memory");
    }
    asm volatile("s_waitcnt vmcnt(0)" ::: "memory");
    __builtin_amdgcn_s_barrier();
    asm volatile("" ::: "memory");
    compute_tile((NKT - 1) & 1);

    #pragma unroll
    for (int i = 0; i < 2; ++i) {
        int pix = p0 + wp * 32 + i * 16 + quad * 4;
        #pragma unroll
        for (int jq = 0; jq < 4; ++jq) {
            int cch = c0 + wq * 64 + jq * 16 + l15;
            float bz = bias[cch];
            float4 v;
            v.x = acc[i][jq][0] + bz;
            v.y = acc[i][jq][1] + bz;
            v.z = acc[i][jq][2] + bz;
            v.w = acc[i][jq][3] + bz;
            float* dst = out + ((size_t)b * CC + cch) * HW + pix;
            *(float4*)dst = v;
        }
    }
}

// ---------------- GEMM3 fallback (f32 w) ----------------
__global__ __launch_bounds__(256) void proj_gemm_kernel(const ushort_t* __restrict__ ao,
                                                        const float* __restrict__ w,
                                                        const float* __restrict__ bias,
                                                        float* __restrict__ out) {
    __shared__ __align__(16) ushort_t lds_p[64 * LP];
    __shared__ __align__(16) ushort_t lds_q[128 * LP];
    const int K = CC;
    int tid = threadIdx.x;
    int b = blockIdx.z;
    int p0 = blockIdx.x * 64;
    int c0 = blockIdx.y * 128;
    int lane = tid & 63, wv = tid >> 6;
    int wp = wv & 1, wq = wv >> 1;
    int quad = lane >> 4, l15 = lane & 15;

    f32x4 acc[2][4];
    #pragma unroll
    for (int i = 0; i < 2; ++i)
        #pragma unroll
        for (int jq = 0; jq < 4; ++jq) acc[i][jq] = (f32x4){0.f, 0.f, 0.f, 0.f};

    const ushort_t* abase = ao + ((size_t)b * HEADS) * HW * DD;

    for (int kt = 0; kt < K / 32; ++kt) {
        __syncthreads();
        {
            int row = tid >> 2, k8 = (tid & 3) * 8;
            uint4_t u = *(const uint4_t*)(abase + ((size_t)kt * HW + p0 + row) * DD + k8);
            *(uint4_t*)&lds_p[row * LP + k8] = u;
        }
        #pragma unroll
        for (int r = 0; r < 2; ++r) {
            int chunk = tid + r * 256;
            int row = chunk >> 2, k8 = (chunk & 3) * 8;
            const float* src = w + (size_t)(c0 + row) * K + kt * 32 + k8;
            float4 f0 = *(const float4*)src;
            float4 f1 = *(const float4*)(src + 4);
            uint4_t u;
            u[0] = pack2(f0.x, f0.y);
            u[1] = pack2(f0.z, f0.w);
            u[2] = pack2(f1.x, f1.y);
            u[3] = pack2(f1.z, f1.w);
            *(uint4_t*)&lds_q[row * LP + k8] = u;
        }
        __syncthreads();
        bf16x8 afrag[2], bfrag[4];
        #pragma unroll
        for (int i = 0; i < 2; ++i)
            afrag[i] = *(const bf16x8*)&lds_p[(wp * 32 + i * 16 + l15) * LP + quad * 8];
        #pragma unroll
        for (int jq = 0; jq < 4; ++jq)
            bfrag[jq] = *(const bf16x8*)&lds_q[(wq * 64 + jq * 16 + l15) * LP + quad * 8];
        #pragma unroll
        for (int i = 0; i < 2; ++i)
            #pragma unroll
            for (int jq = 0; jq < 4; ++jq)
                acc[i][jq] = __builtin_amdgcn_mfma_f32_16x16x32_bf16(afrag[i], bfrag[jq],
                                                                     acc[i][jq], 0, 0, 0);
    }
    #pragma unroll
    for (int i = 0; i < 2; ++i) {
        int pix = p0 + wp * 32 + i * 16 + quad * 4;
        #pragma unroll
        for (int jq = 0; jq < 4; ++jq) {
            int cch = c0 + wq * 64 + jq * 16 + l15;
            float bz = bias[cch];
            float4 v;
            v.x = acc[i][jq][0] + bz;
            v.y = acc[i][jq][1] + bz;
            v.z = acc[i][jq][2] + bz;
            v.w = acc[i][jq][3] + bz;
            float* dst = out + ((size_t)b * CC + cch) * HW + pix;
            *(float4*)dst = v;
        }
    }
}

extern "C" void kernel_launch(void* const* d_in, const int* in_sizes, int n_in,
                              void* d_out, int out_size, void* d_ws, size_t ws_size,
                              hipStream_t stream) {
    const float* x = (const float*)d_in[0];
    const float* qkv_w = (const float*)d_in[1];
    const float* rpb = (const float*)d_in[2];
    const float* proj_w = (const float*)d_in[3];
    const float* proj_b = (const float*)d_in[4];
    float* out = (float*)d_out;

    size_t need_min = 3 * PLANE * sizeof(ushort_t);                       // 73.5 MB
    size_t need_full = (4 * PLANE + WQ_ELEMS + WP_ELEMS) * sizeof(ushort_t);  // 100 MB

    if (ws_size < need_min) {
        zero_out_f32<<<dim3((int)((OUT_TOT + 255) / 256)), dim3(256), 0, stream>>>(out);
        return;
    }

    ushort_t* qkv = (ushort_t*)d_ws;                 // q/k/v: 3 bf16 planes

    if (ws_size >= need_full) {
        ushort_t* xbf = qkv + 3 * PLANE;             // bf16 x, [b][hw][c] (TRANSPOSED)
        ushort_t* wqb = qkv + 4 * PLANE;             // bf16 qkv_w
        ushort_t* wpb = wqb + WQ_ELEMS;              // bf16 proj_w

        xpose_cvt<<<dim3(49, 8, 8), dim3(256), 0, stream>>>(x, xbf);
        cvt_weights<<<dim3((WQ_ELEMS / 8 + WP_ELEMS / 8 + 255) / 256), dim3(256), 0,
                      stream>>>(qkv_w, wqb, WQ_ELEMS / 8, proj_w, wpb, WP_ELEMS / 8);

        qkv_gemm_bf16<<<dim3(49, 6, 8), dim3(256), 0, stream>>>(xbf, wqb, qkv);
        attn_mfma<<<dim3(49, HEADS, BATCH), dim3(256), 0, stream>>>(qkv, rpb);
        proj_gemm_bf16<<<dim3(49, 4, 8), dim3(256), 0, stream>>>(qkv, wpb, proj_b, out);
    } else {
        qkv_gemm_kernel<<<dim3(49, 12, 8), dim3(256), 0, stream>>>(x, qkv_w, qkv);
        attn_mfma<<<dim3(49, HEADS, BATCH), dim3(256), 0, stream>>>(qkv, rpb);
        proj_gemm_kernel<<<dim3(49, 4, 8), dim3(256), 0, stream>>>(qkv, proj_w, proj_b, out);
    }
}

// Round 15
// 247.167 us; speedup vs baseline: 1.1492x; 1.0327x over previous
//
#include <hip/hip_runtime.h>

// NeighborhoodAttention2D: B=8, C=512, H=W=56, heads=16, d=32, KSZ=7
// Round 23: REVERT qkv to r20 dbuf+vmcnt(5) (tri-buffer refuted: Occ 19.5%,
// FETCH 70MB, 80us). qkv is at its 2-barrier structural ceiling (~71us) —
// three structure theories failed identically; stop touching it.
// NEW: proj retile 64px x 256c (was 64x128): 16 MFMA/wave/step (= qkv's
// measured-best ratio, was 8), 4x A-reuse, grid 784 (3 blk/CU @ 40KB dbuf).
// Same 5-loads/thread vmcnt(5) skeleton, same swizzle involution, same
// epilogue convention as the green code. attn/prep/fallbacks = r20 exact.

typedef unsigned short ushort_t;
typedef short bf16x8 __attribute__((ext_vector_type(8)));      // 8 bf16 = 4 VGPRs
typedef short bf16x4 __attribute__((ext_vector_type(4)));      // 4 bf16 = 2 VGPRs
typedef float f32x4 __attribute__((ext_vector_type(4)));       // MFMA C/D frag
typedef unsigned int uint4_t __attribute__((ext_vector_type(4)));
typedef unsigned int uint2_t __attribute__((ext_vector_type(2)));

#define BATCH 8
#define HEADS 16
#define HW 3136
#define HH 56
#define DD 32
#define CC 512
#define PLANE ((size_t)BATCH * HEADS * HW * DD)   // 12,845,056 elems (= B*C*HW)
#define OUT_TOT ((size_t)BATCH * CC * HW)
#define LP 40                                      // fallback-GEMM LDS pitch
#define LPG 32                                     // gload_lds GEMM pitch (linear rows)

// attention tile geometry
#define KT 14
#define KP 32
#define VPP 228

#define WQ_ELEMS (1536 * 512)
#define WP_ELEMS (512 * 512)

__device__ __forceinline__ ushort_t f2bf(float f) {
    union { float f; unsigned int i; } v; v.f = f;
    unsigned int r = v.i + 0x7FFFu + ((v.i >> 16) & 1u);   // RNE
    return (ushort_t)(r >> 16);
}
__device__ __forceinline__ unsigned int pack2(float a, float b) {
    return (unsigned int)f2bf(a) | ((unsigned int)f2bf(b) << 16);
}

__device__ __forceinline__ f32x4 mfma16x16x16(bf16x4 a, bf16x4 b, f32x4 c) {
#if __has_builtin(__builtin_amdgcn_mfma_f32_16x16x16bf16_1k)
    return __builtin_amdgcn_mfma_f32_16x16x16bf16_1k(a, b, c, 0, 0, 0);
#else
    f32x4 d;
    asm("v_mfma_f32_16x16x16_bf16 %0, %1, %2, %3" : "=v"(d) : "v"(a), "v"(b), "v"(c));
    return d;
#endif
}

// async global->LDS, 16B per lane; lds dest must be wave-linear (base + lane*16)
__device__ __forceinline__ void gload16(const ushort_t* g, ushort_t* l) {
    __builtin_amdgcn_global_load_lds(
        (const __attribute__((address_space(1))) unsigned int*)g,
        (__attribute__((address_space(3))) unsigned int*)l, 16, 0, 0);
}

__global__ __launch_bounds__(256) void zero_out_f32(float* __restrict__ out) {
    size_t idx = (size_t)blockIdx.x * 256 + threadIdx.x;
    if (idx < OUT_TOT) out[idx] = 0.f;
}

// ---------------- prep: both weight matrices f32 -> bf16, one launch ----------------
__global__ __launch_bounds__(256) void cvt_weights(const float* __restrict__ wa,
                                                   ushort_t* __restrict__ da, int n8a,
                                                   const float* __restrict__ wb,
                                                   ushort_t* __restrict__ db, int n8b) {
    int idx = blockIdx.x * 256 + threadIdx.x;
    const float* s;
    ushort_t* d;
    int i;
    if (idx < n8a) {
        s = wa; d = da; i = idx;
    } else {
        i = idx - n8a;
        if (i >= n8b) return;
        s = wb; d = db;
    }
    const float4* sp = (const float4*)s + (size_t)i * 2;
    float4 f0 = sp[0], f1 = sp[1];
    uint4_t u;
    u[0] = pack2(f0.x, f0.y);
    u[1] = pack2(f0.z, f0.w);
    u[2] = pack2(f1.x, f1.y);
    u[3] = pack2(f1.z, f1.w);
    *(uint4_t*)(d + (size_t)i * 8) = u;
}

// ---------------- prep: x [b][c][hw] f32 -> xbf [b][hw][c] bf16 ----------------
__global__ __launch_bounds__(256) void xpose_cvt(const float* __restrict__ x,
                                                 ushort_t* __restrict__ xb) {
    __shared__ ushort_t T[64 * 64];                // 8192 B
    int tid = threadIdx.x;
    int hw0 = blockIdx.x * 64;
    int c0 = blockIdx.y * 64;
    int b = blockIdx.z;

    int cr = tid >> 2, hq = tid & 3;
    const float* src = x + ((size_t)b * CC + c0 + cr) * HW + hw0 + hq * 16;
    float4 f0 = *(const float4*)(src);
    float4 f1 = *(const float4*)(src + 4);
    float4 f2 = *(const float4*)(src + 8);
    float4 f3 = *(const float4*)(src + 12);
    uint4_t u0, u1;
    u0[0] = pack2(f0.x, f0.y); u0[1] = pack2(f0.z, f0.w);
    u0[2] = pack2(f1.x, f1.y); u0[3] = pack2(f1.z, f1.w);
    u1[0] = pack2(f2.x, f2.y); u1[1] = pack2(f2.z, f2.w);
    u1[2] = pack2(f3.x, f3.y); u1[3] = pack2(f3.z, f3.w);
    int sw = ((cr >> 4) & 3) << 4;
    int col0 = (hq * 16) ^ sw;
    *(uint4_t*)&T[cr * 64 + col0] = u0;
    *(uint4_t*)&T[cr * 64 + col0 + 8] = u1;

    __syncthreads();

    int p = tid >> 2, cq = tid & 3;
    int pc = p ^ (cq << 4);
    unsigned vv[8];
    #pragma unroll
    for (int j = 0; j < 16; j += 2) {
        unsigned a = T[(cq * 16 + j) * 64 + pc];
        unsigned b2 = T[(cq * 16 + j + 1) * 64 + pc];
        vv[j >> 1] = a | (b2 << 16);
    }
    ushort_t* dst = xb + ((size_t)b * HW + hw0 + p) * CC + c0 + cq * 16;
    uint4_t w0, w1;
    w0[0] = vv[0]; w0[1] = vv[1]; w0[2] = vv[2]; w0[3] = vv[3];
    w1[0] = vv[4]; w1[1] = vv[5]; w1[2] = vv[6]; w1[3] = vv[7];
    *(uint4_t*)&dst[0] = w0;
    *(uint4_t*)&dst[8] = w1;
}

// ---------------- GEMM1 (bf16): qkv^T = wq (1536x512) . xb ([b][hw][c]) ----------
// 256n x 64px tile, dbuf + T4 counted vmcnt(5), raw barriers, XCD swizzle (r20).
__global__ __launch_bounds__(256) void qkv_gemm_bf16(const ushort_t* __restrict__ xb,
                                                     const ushort_t* __restrict__ w,
                                                     ushort_t* __restrict__ qkv) {
    __shared__ __align__(16) ushort_t lds_p[2][256 * LPG];   // 2 x 16384 B
    __shared__ __align__(16) ushort_t lds_q[2][64 * LPG];    // 2 x  4096 B
    int tid = threadIdx.x;

    // T1 XCD swizzle: grid 49x6x8 = 2352 = 8 x 294; each XCD chunk = one batch b
    int lid = ((int)blockIdx.z * 6 + (int)blockIdx.y) * 49 + (int)blockIdx.x;
    int wl = (lid & 7) * 294 + (lid >> 3);
    int p0 = (wl % 49) * 64;
    int rest = wl / 49;
    int n0 = (rest % 6) * 256;
    int b = rest / 6;

    int lane = tid & 63, wv = tid >> 6;
    int wp = wv & 1, wq = wv >> 1;
    int quad = lane >> 4, l15 = lane & 15;

    f32x4 acc[8][2];
    #pragma unroll
    for (int i = 0; i < 8; ++i)
        #pragma unroll
        for (int jq = 0; jq < 2; ++jq) acc[i][jq] = (f32x4){0.f, 0.f, 0.f, 0.f};

    int swz = (l15 >> 1) & 3;                  // fragment-read swizzle (row->chunk)
    int cha = (quad ^ swz) * 8;                // swizzled k-octet for frag reads

    // per-thread staging descriptors (constant across kt)
    int ca_row[4], ca_k8[4];
    #pragma unroll
    for (int r = 0; r < 4; ++r) {
        int c = r * 256 + tid;
        ca_row[r] = c >> 2;
        ca_k8[r] = ((c & 3) ^ ((c >> 3) & 3)) * 8;
    }
    int cb_row = tid >> 2;
    int cb_k8 = ((tid & 3) ^ ((tid >> 3) & 3)) * 8;

    auto compute_tile = [&](int cur) {
        bf16x8 afrag[8], bfrag[2];
        #pragma unroll
        for (int i = 0; i < 8; ++i)
            afrag[i] = *(const bf16x8*)&lds_p[cur][(wp * 128 + i * 16 + l15) * LPG + cha];
        #pragma unroll
        for (int jq = 0; jq < 2; ++jq)
            bfrag[jq] = *(const bf16x8*)&lds_q[cur][(wq * 32 + jq * 16 + l15) * LPG + cha];
        #pragma unroll
        for (int i = 0; i < 8; ++i)
            #pragma unroll
            for (int jq = 0; jq < 2; ++jq)
                acc[i][jq] = __builtin_amdgcn_mfma_f32_16x16x32_bf16(afrag[i], bfrag[jq],
                                                                     acc[i][jq], 0, 0, 0);
    };

    const int NKT = CC / 32;                   // 16
    // prologue: stage tile 0 into buffer 0, full drain once
    #pragma unroll
    for (int r = 0; r < 4; ++r)
        gload16(w + (size_t)(n0 + ca_row[r]) * CC + ca_k8[r],
                &lds_p[0][(r * 256 + tid) * 8]);
    gload16(xb + ((size_t)b * HW + p0 + cb_row) * CC + cb_k8, &lds_q[0][tid * 8]);
    asm volatile("s_waitcnt vmcnt(0)" ::: "memory");
    __builtin_amdgcn_s_barrier();
    asm volatile("" ::: "memory");

    for (int kt = 0; kt < NKT - 1; ++kt) {
        int cur = kt & 1;
        int ko = (kt + 1) * 32;
        #pragma unroll
        for (int r = 0; r < 4; ++r)            // stage tile kt+1 into buf[cur^1]
            gload16(w + (size_t)(n0 + ca_row[r]) * CC + ko + ca_k8[r],
                    &lds_p[cur ^ 1][(r * 256 + tid) * 8]);
        gload16(xb + ((size_t)b * HW + p0 + cb_row) * CC + ko + cb_k8,
                &lds_q[cur ^ 1][tid * 8]);
        // T4: wait ONLY for tile kt's 5 loads (oldest); kt+1's 5 stay in flight
        asm volatile("s_waitcnt vmcnt(5)" ::: "memory");
        __builtin_amdgcn_s_barrier();
        asm volatile("" ::: "memory");
        compute_tile(cur);
        asm volatile("" ::: "memory");
        __builtin_amdgcn_s_barrier();          // readers of buf[cur] done before next staging
        asm volatile("" ::: "memory");
    }
    asm volatile("s_waitcnt vmcnt(0)" ::: "memory");
    __builtin_amdgcn_s_barrier();
    asm volatile("" ::: "memory");
    compute_tile((NKT - 1) & 1);

    const float qscale = 0.17677669529663687f;   // 1/sqrt(32)
    #pragma unroll
    for (int i = 0; i < 8; ++i) {
        int nbase = n0 + wp * 128 + i * 16 + quad * 4;
        int which = nbase >> 9;
        int h = (nbase >> 5) & 15;
        int dch = nbase & 31;
        float sc = (which == 0) ? qscale : 1.0f;
        #pragma unroll
        for (int jq = 0; jq < 2; ++jq) {
            int pix = p0 + wq * 32 + jq * 16 + l15;
            uint2_t v;
            v[0] = pack2(acc[i][jq][0] * sc, acc[i][jq][1] * sc);
            v[1] = pack2(acc[i][jq][2] * sc, acc[i][jq][3] * sc);
            ushort_t* dst = qkv + (size_t)which * PLANE +
                            ((((size_t)b * HEADS + h) * HW + pix) * DD + dch);
            *(uint2_t*)dst = v;
        }
    }
}

// ---------------- GEMM1 fallback (f32 inputs) ----------------
__global__ __launch_bounds__(256) void qkv_gemm_kernel(const float* __restrict__ x,
                                                       const float* __restrict__ w,
                                                       ushort_t* __restrict__ qkv) {
    __shared__ __align__(16) ushort_t lds_p[128 * LP];
    __shared__ __align__(16) ushort_t lds_q[64 * LP];
    const int K = CC;
    int tid = threadIdx.x;
    int b = blockIdx.z;
    int n0 = blockIdx.y * 128;
    int p0 = blockIdx.x * 64;
    int lane = tid & 63, wv = tid >> 6;
    int wp = wv & 1, wq = wv >> 1;
    int quad = lane >> 4, l15 = lane & 15;

    f32x4 acc[4][2];
    #pragma unroll
    for (int i = 0; i < 4; ++i)
        #pragma unroll
        for (int jq = 0; jq < 2; ++jq) acc[i][jq] = (f32x4){0.f, 0.f, 0.f, 0.f};

    int spx = tid & 63;
    int sk8 = (tid >> 6) * 8;

    for (int kt = 0; kt < K / 32; ++kt) {
        __syncthreads();
        #pragma unroll
        for (int r = 0; r < 2; ++r) {
            int chunk = tid + r * 256;
            int row = chunk >> 2, k8 = (chunk & 3) * 8;
            const float* src = w + (size_t)(n0 + row) * K + kt * 32 + k8;
            float4 f0 = *(const float4*)src;
            float4 f1 = *(const float4*)(src + 4);
            uint4_t u;
            u[0] = pack2(f0.x, f0.y);
            u[1] = pack2(f0.z, f0.w);
            u[2] = pack2(f1.x, f1.y);
            u[3] = pack2(f1.z, f1.w);
            *(uint4_t*)&lds_p[row * LP + k8] = u;
        }
        {
            const float* xcol = x + ((size_t)b * CC + kt * 32 + sk8) * HW + p0 + spx;
            float v0 = xcol[0];
            float v1 = xcol[(size_t)HW];
            float v2 = xcol[(size_t)2 * HW];
            float v3 = xcol[(size_t)3 * HW];
            float v4 = xcol[(size_t)4 * HW];
            float v5 = xcol[(size_t)5 * HW];
            float v6 = xcol[(size_t)6 * HW];
            float v7 = xcol[(size_t)7 * HW];
            uint4_t u;
            u[0] = pack2(v0, v1);
            u[1] = pack2(v2, v3);
            u[2] = pack2(v4, v5);
            u[3] = pack2(v6, v7);
            *(uint4_t*)&lds_q[spx * LP + sk8] = u;
        }
        __syncthreads();
        bf16x8 afrag[4], bfrag[2];
        #pragma unroll
        for (int i = 0; i < 4; ++i)
            afrag[i] = *(const bf16x8*)&lds_p[(wp * 64 + i * 16 + l15) * LP + quad * 8];
        #pragma unroll
        for (int jq = 0; jq < 2; ++jq)
            bfrag[jq] = *(const bf16x8*)&lds_q[(wq * 32 + jq * 16 + l15) * LP + quad * 8];
        #pragma unroll
        for (int i = 0; i < 4; ++i)
            #pragma unroll
            for (int jq = 0; jq < 2; ++jq)
                acc[i][jq] = __builtin_amdgcn_mfma_f32_16x16x32_bf16(afrag[i], bfrag[jq],
                                                                     acc[i][jq], 0, 0, 0);
    }
    const float qscale = 0.17677669529663687f;
    #pragma unroll
    for (int i = 0; i < 4; ++i) {
        int nbase = n0 + wp * 64 + i * 16 + quad * 4;
        int which = nbase >> 9;
        int h = (nbase >> 5) & 15;
        int dch = nbase & 31;
        float sc = (which == 0) ? qscale : 1.0f;
        #pragma unroll
        for (int jq = 0; jq < 2; ++jq) {
            int pix = p0 + wq * 32 + jq * 16 + l15;
            uint2_t v;
            v[0] = pack2(acc[i][jq][0] * sc, acc[i][jq][1] * sc);
            v[1] = pack2(acc[i][jq][2] * sc, acc[i][jq][3] * sc);
            ushort_t* dst = qkv + (size_t)which * PLANE +
                            ((((size_t)b * HEADS + h) * HW + pix) * DD + dch);
            *(uint2_t*)dst = v;
        }
    }
}

// ---------------- MFMA attention: one block per (b, h, 8x8 query tile) ----------------
__global__ __launch_bounds__(256, 4) void attn_mfma(ushort_t* __restrict__ qkv,
                                                    const float* __restrict__ rpb) {
    __shared__ __align__(16) ushort_t Klds[224 * KP];        // 14336 B, [kk][d]
    __shared__ __align__(16) ushort_t Vlds[DD * VPP];        // 14592 B, [d][kk]
    __shared__ float rpbl[169];                              //   676 B

    int tid = threadIdx.x;

    // T1 XCD swizzle: grid 49x16x8 = 6272 = 8 x 784; each XCD chunk = one batch b
    int lid = ((int)blockIdx.z * 16 + (int)blockIdx.y) * 49 + (int)blockIdx.x;
    int wl = (lid & 7) * 784 + (lid >> 3);
    int tile = wl % 49;
    int rest = wl / 49;
    int h = rest % 16;
    int b = rest / 16;

    int ti = tile / 7, tj = tile - ti * 7;
    int i0 = ti * 8, j0 = tj * 8;
    int kr0 = min(max(i0 - 3, 0), HH - 14);
    int kc0 = min(max(j0 - 3, 0), HH - 14);

    const ushort_t* qp = qkv + (((size_t)b * HEADS + h) * HW) * DD;
    const ushort_t* kp = qp + PLANE;
    const ushort_t* vp = qp + 2 * PLANE;

    if (tid < 169) rpbl[tid] = rpb[h * 169 + tid];

    #pragma unroll
    for (int r = 0; r < 4; ++r) {
        int idx = tid + r * 256;
        if (idx < 784) {
            int u = idx / 56;
            int rem = idx - u * 56;
            int w = rem >> 2, d8 = (rem & 3) << 3;
            const ushort_t* src = kp + ((size_t)((kr0 + u) * HH + kc0 + w)) * DD + d8;
            *(uint4_t*)&Klds[(u * 16 + w) * KP + d8] = *(const uint4_t*)src;
        } else if (idx < 896) {
            int z = idx - 784;
            int u = z >> 3, rem = z & 7;
            int w = 14 + (rem >> 2), d8 = (rem & 3) << 3;
            *(uint4_t*)&Klds[(u * 16 + w) * KP + d8] = (uint4_t){0, 0, 0, 0};
        }
    }
    #pragma unroll
    for (int rr = 0; rr < 2; ++rr) {
        int idx = tid + rr * 256;
        if (idx < 448) {
            int u = idx >> 5, rem = idx & 31;
            int pr = rem >> 2, d8 = (rem & 3) << 3;
            int kk0 = u * 16 + pr * 2;
            if (pr < 7) {
                const ushort_t* s0 = vp + ((size_t)((kr0 + u) * HH + kc0 + pr * 2)) * DD + d8;
                uint4_t a = *(const uint4_t*)s0;
                uint4_t c = *(const uint4_t*)(s0 + DD);
                #pragma unroll
                for (int e = 0; e < 4; ++e) {
                    unsigned lo = (a[e] & 0xFFFFu) | (c[e] << 16);
                    unsigned hi = (a[e] >> 16) | (c[e] & 0xFFFF0000u);
                    *(unsigned*)&Vlds[(d8 + 2 * e) * VPP + kk0] = lo;
                    *(unsigned*)&Vlds[(d8 + 2 * e + 1) * VPP + kk0] = hi;
                }
            } else {
                #pragma unroll
                for (int e = 0; e < 8; ++e)
                    *(unsigned*)&Vlds[(d8 + e) * VPP + kk0] = 0;
            }
        }
    }

    int lane = tid & 63, wv = tid >> 6;
    int l15 = lane & 15, quad = lane >> 4;
    int q_idx = wv * 16 + l15;
    int qi = i0 + (q_idx >> 3), qj = j0 + (q_idx & 7);
    int si = min(max(qi - 3, 0), HH - 7);
    int sj = min(max(qj - 3, 0), HH - 7);

    bf16x8 bq = *(const bf16x8*)(qp + ((size_t)(qi * HH + qj)) * DD + quad * 8);

    int jbase = kc0 + quad * 4 - sj;
    int cbase = kc0 + quad * 4 - qj + 6;
    int coff[4];
    bool cok[4];
    #pragma unroll
    for (int r2 = 0; r2 < 4; ++r2) {
        cok[r2] = (unsigned)(jbase + r2) <= 6u;
        coff[r2] = min(max(cbase + r2, 0), 12);
    }

    __syncthreads();

    f32x4 lg[KT];
    f32x4 zf = {0.f, 0.f, 0.f, 0.f};
    __builtin_amdgcn_s_setprio(1);             // T5: QK^T cluster
    #pragma unroll
    for (int t = 0; t < KT; ++t) {
        bf16x8 ak = *(const bf16x8*)&Klds[(t * 16 + l15) * KP + quad * 8];
        lg[t] = __builtin_amdgcn_mfma_f32_16x16x32_bf16(ak, bq, zf, 0, 0, 0);
    }
    __builtin_amdgcn_s_setprio(0);

    int abase = kr0 - qi + 6;
    #pragma unroll
    for (int t = 0; t < KT; ++t) {
        bool rok = (unsigned)(kr0 + t - si) <= 6u;
        int arow = min(max(abase + t, 0), 12);
        const float* br = &rpbl[arow * 13];
        #pragma unroll
        for (int r2 = 0; r2 < 4; ++r2) {
            float bias = br[coff[r2]];
            lg[t][r2] = (rok && cok[r2]) ? lg[t][r2] + bias : -1e30f;
        }
    }

    float m = -1e30f;
    #pragma unroll
    for (int t = 0; t < KT; ++t)
        #pragma unroll
        for (int r2 = 0; r2 < 4; ++r2) m = fmaxf(m, lg[t][r2]);
    m = fmaxf(m, __shfl_xor(m, 16));
    m = fmaxf(m, __shfl_xor(m, 32));
    float s = 0.f;
    #pragma unroll
    for (int t = 0; t < KT; ++t)
        #pragma unroll
        for (int r2 = 0; r2 < 4; ++r2) {
            float e = __expf(lg[t][r2] - m);
            lg[t][r2] = e;
            s += e;
        }
    s += __shfl_xor(s, 16);
    s += __shfl_xor(s, 32);
    float inv = 1.f / s;

    bf16x4 pb[KT];
    #pragma unroll
    for (int t = 0; t < KT; ++t) {
        union { uint2_t u; bf16x4 v; } cv;
        cv.u[0] = pack2(lg[t][0], lg[t][1]);
        cv.u[1] = pack2(lg[t][2], lg[t][3]);
        pb[t] = cv.v;
    }

    f32x4 acc0 = zf, acc1 = zf;
    __builtin_amdgcn_s_setprio(1);             // T5: PV cluster
    #pragma unroll
    for (int t = 0; t < KT; ++t) {
        bf16x4 bv0 = *(const bf16x4*)&Vlds[l15 * VPP + t * 16 + quad * 4];
        bf16x4 bv1 = *(const bf16x4*)&Vlds[(16 + l15) * VPP + t * 16 + quad * 4];
        acc0 = mfma16x16x16(pb[t], bv0, acc0);
        acc1 = mfma16x16x16(pb[t], bv1, acc1);
    }
    __builtin_amdgcn_s_setprio(0);

    ushort_t* op = qkv + (((size_t)b * HEADS + h) * HW) * DD;
    #pragma unroll
    for (int e = 0; e < 4; ++e) {
        float invq = __shfl(inv, quad * 4 + e);
        int q2 = wv * 16 + quad * 4 + e;
        int pix = (i0 + (q2 >> 3)) * HH + j0 + (q2 & 7);
        op[(size_t)pix * DD + l15] = f2bf(acc0[e] * invq);
        op[(size_t)pix * DD + 16 + l15] = f2bf(acc1[e] * invq);
    }
}

// ---------------- GEMM3 (bf16): y = attn_out . wpb^T + b; OUT f32 ----------------
// NEW 64px x 256c tile: per-wave 64x64 output (acc[4][4], 16 MFMA/step = qkv ratio),
// dbuf + counted vmcnt(5), raw barriers, XCD swizzle. LDS 40KB -> 3 blocks/CU.
__global__ __launch_bounds__(256) void proj_gemm_bf16(const ushort_t* __restrict__ ao,
                                                      const ushort_t* __restrict__ w,
                                                      const float* __restrict__ bias,
                                                      float* __restrict__ out) {
    __shared__ __align__(16) ushort_t lds_p[2][64 * LPG];    // 2 x  4096 B (pixels)
    __shared__ __align__(16) ushort_t lds_q[2][256 * LPG];   // 2 x 16384 B (c-rows)
    int tid = threadIdx.x;

    // T1 XCD swizzle: grid 49x2x8 = 784 = 8 x 98; each XCD chunk = one batch b
    int lid = ((int)blockIdx.z * 2 + (int)blockIdx.y) * 49 + (int)blockIdx.x;
    int wl = (lid & 7) * 98 + (lid >> 3);
    int p0 = (wl % 49) * 64;
    int rest = wl / 49;                         // 0..15
    int c0 = (rest & 1) * 256;
    int b = rest >> 1;

    int lane = tid & 63, wv = tid >> 6;         // wave wv owns c-strip [wv*64, wv*64+64)
    int quad = lane >> 4, l15 = lane & 15;

    f32x4 acc[4][4];
    #pragma unroll
    for (int i = 0; i < 4; ++i)
        #pragma unroll
        for (int jq = 0; jq < 4; ++jq) acc[i][jq] = (f32x4){0.f, 0.f, 0.f, 0.f};

    const ushort_t* abase = ao + ((size_t)b * HEADS) * HW * DD;
    int swz = (l15 >> 1) & 3;
    int cha = (quad ^ swz) * 8;

    int ca_row = tid >> 2;                      // A: 256 chunks (64 pixel rows)
    int ca_k8 = ((tid & 3) ^ ((tid >> 3) & 3)) * 8;
    int cb_row[4], cb_k8[4];                    // B: 1024 chunks (256 weight rows)
    #pragma unroll
    for (int r = 0; r < 4; ++r) {
        int c = r * 256 + tid;
        cb_row[r] = c >> 2;
        cb_k8[r] = ((c & 3) ^ ((c >> 3) & 3)) * 8;
    }

    auto stage = [&](int buf, int kt) {
        gload16(abase + ((size_t)kt * HW + p0 + ca_row) * DD + ca_k8,
                &lds_p[buf][tid * 8]);
        #pragma unroll
        for (int r = 0; r < 4; ++r)
            gload16(w + (size_t)(c0 + cb_row[r]) * CC + kt * 32 + cb_k8[r],
                    &lds_q[buf][(r * 256 + tid) * 8]);
    };

    auto compute_tile = [&](int cur) {
        bf16x8 afrag[4], bfrag[4];
        #pragma unroll
        for (int i = 0; i < 4; ++i)
            afrag[i] = *(const bf16x8*)&lds_p[cur][(i * 16 + l15) * LPG + cha];
        #pragma unroll
        for (int jq = 0; jq < 4; ++jq)
            bfrag[jq] = *(const bf16x8*)&lds_q[cur][(wv * 64 + jq * 16 + l15) * LPG + cha];
        #pragma unroll
        for (int i = 0; i < 4; ++i)
            #pragma unroll
            for (int jq = 0; jq < 4; ++jq)
                acc[i][jq] = __builtin_amdgcn_mfma_f32_16x16x32_bf16(afrag[i], bfrag[jq],
                                                                     acc[i][jq], 0, 0, 0);
    };

    const int NKT = CC / 32;
    // prologue: stage tile 0 into buffer 0, full drain once
    stage(0, 0);
    asm volatile("s_waitcnt vmcnt(0)" ::: "memory");
    __builtin_amdgcn_s_barrier();
    asm volatile("" ::: "memory");

    for (int kt = 0; kt < NKT - 1; ++kt) {
        int cur = kt & 1;
        stage(cur ^ 1, kt + 1);
        // T4: wait ONLY for tile kt's 5 loads; kt+1's 5 stay in flight
        asm volatile("s_waitcnt vmcnt(5)" ::: "memory");
        __builtin_amdgcn_s_barrier();
        asm volatile("" ::: "memory");
        compute_tile(cur);
        asm volatile("" ::: "memory");
        __builtin_amdgcn_s_barrier();
        asm volatile("" ::: "memory");
    }
    asm volatile("s_waitcnt vmcnt(0)" ::: "memory");
    __builtin_amdgcn_s_barrier();
    asm volatile("" ::: "memory");
    compute_tile((NKT - 1) & 1);

    #pragma unroll
    for (int i = 0; i < 4; ++i) {
        int pix = p0 + i * 16 + quad * 4;       // 4 consecutive pixels (quad*4+e)
        #pragma unroll
        for (int jq = 0; jq < 4; ++jq) {
            int cch = c0 + wv * 64 + jq * 16 + l15;
            float bz = bias[cch];
            float4 v;
            v.x = acc[i][jq][0] + bz;
            v.y = acc[i][jq][1] + bz;
            v.z = acc[i][jq][2] + bz;
            v.w = acc[i][jq][3] + bz;
            float* dst = out + ((size_t)b * CC + cch) * HW + pix;
            *(float4*)dst = v;
        }
    }
}

// ---------------- GEMM3 fallback (f32 w) ----------------
__global__ __launch_bounds__(256) void proj_gemm_kernel(const ushort_t* __restrict__ ao,
                                                        const float* __restrict__ w,
                                                        const float* __restrict__ bias,
                                                        float* __restrict__ out) {
    __shared__ __align__(16) ushort_t lds_p[64 * LP];
    __shared__ __align__(16) ushort_t lds_q[128 * LP];
    const int K = CC;
    int tid = threadIdx.x;
    int b = blockIdx.z;
    int p0 = blockIdx.x * 64;
    int c0 = blockIdx.y * 128;
    int lane = tid & 63, wv = tid >> 6;
    int wp = wv & 1, wq = wv >> 1;
    int quad = lane >> 4, l15 = lane & 15;

    f32x4 acc[2][4];
    #pragma unroll
    for (int i = 0; i < 2; ++i)
        #pragma unroll
        for (int jq = 0; jq < 4; ++jq) acc[i][jq] = (f32x4){0.f, 0.f, 0.f, 0.f};

    const ushort_t* abase = ao + ((size_t)b * HEADS) * HW * DD;

    for (int kt = 0; kt < K / 32; ++kt) {
        __syncthreads();
        {
            int row = tid >> 2, k8 = (tid & 3) * 8;
            uint4_t u = *(const uint4_t*)(abase + ((size_t)kt * HW + p0 + row) * DD + k8);
            *(uint4_t*)&lds_p[row * LP + k8] = u;
        }
        #pragma unroll
        for (int r = 0; r < 2; ++r) {
            int chunk = tid + r * 256;
            int row = chunk >> 2, k8 = (chunk & 3) * 8;
            const float* src = w + (size_t)(c0 + row) * K + kt * 32 + k8;
            float4 f0 = *(const float4*)src;
            float4 f1 = *(const float4*)(src + 4);
            uint4_t u;
            u[0] = pack2(f0.x, f0.y);
            u[1] = pack2(f0.z, f0.w);
            u[2] = pack2(f1.x, f1.y);
            u[3] = pack2(f1.z, f1.w);
            *(uint4_t*)&lds_q[row * LP + k8] = u;
        }
        __syncthreads();
        bf16x8 afrag[2], bfrag[4];
        #pragma unroll
        for (int i = 0; i < 2; ++i)
            afrag[i] = *(const bf16x8*)&lds_p[(wp * 32 + i * 16 + l15) * LP + quad * 8];
        #pragma unroll
        for (int jq = 0; jq < 4; ++jq)
            bfrag[jq] = *(const bf16x8*)&lds_q[(wq * 64 + jq * 16 + l15) * LP + quad * 8];
        #pragma unroll
        for (int i = 0; i < 2; ++i)
            #pragma unroll
            for (int jq = 0; jq < 4; ++jq)
                acc[i][jq] = __builtin_amdgcn_mfma_f32_16x16x32_bf16(afrag[i], bfrag[jq],
                                                                     acc[i][jq], 0, 0, 0);
    }
    #pragma unroll
    for (int i = 0; i < 2; ++i) {
        int pix = p0 + wp * 32 + i * 16 + quad * 4;
        #pragma unroll
        for (int jq = 0; jq < 4; ++jq) {
            int cch = c0 + wq * 64 + jq * 16 + l15;
            float bz = bias[cch];
            float4 v;
            v.x = acc[i][jq][0] + bz;
            v.y = acc[i][jq][1] + bz;
            v.z = acc[i][jq][2] + bz;
            v.w = acc[i][jq][3] + bz;
            float* dst = out + ((size_t)b * CC + cch) * HW + pix;
            *(float4*)dst = v;
        }
    }
}

extern "C" void kernel_launch(void* const* d_in, const int* in_sizes, int n_in,
                              void* d_out, int out_size, void* d_ws, size_t ws_size,
                              hipStream_t stream) {
    const float* x = (const float*)d_in[0];
    const float* qkv_w = (const float*)d_in[1];
    const float* rpb = (const float*)d_in[2];
    const float* proj_w = (const float*)d_in[3];
    const float* proj_b = (const float*)d_in[4];
    float* out = (float*)d_out;

    size_t need_min = 3 * PLANE * sizeof(ushort_t);                       // 73.5 MB
    size_t need_full = (4 * PLANE + WQ_ELEMS + WP_ELEMS) * sizeof(ushort_t);  // 100 MB

    if (ws_size < need_min) {
        zero_out_f32<<<dim3((int)((OUT_TOT + 255) / 256)), dim3(256), 0, stream>>>(out);
        return;
    }

    ushort_t* qkv = (ushort_t*)d_ws;                 // q/k/v: 3 bf16 planes

    if (ws_size >= need_full) {
        ushort_t* xbf = qkv + 3 * PLANE;             // bf16 x, [b][hw][c] (TRANSPOSED)
        ushort_t* wqb = qkv + 4 * PLANE;             // bf16 qkv_w
        ushort_t* wpb = wqb + WQ_ELEMS;              // bf16 proj_w

        xpose_cvt<<<dim3(49, 8, 8), dim3(256), 0, stream>>>(x, xbf);
        cvt_weights<<<dim3((WQ_ELEMS / 8 + WP_ELEMS / 8 + 255) / 256), dim3(256), 0,
                      stream>>>(qkv_w, wqb, WQ_ELEMS / 8, proj_w, wpb, WP_ELEMS / 8);

        qkv_gemm_bf16<<<dim3(49, 6, 8), dim3(256), 0, stream>>>(xbf, wqb, qkv);
        attn_mfma<<<dim3(49, HEADS, BATCH), dim3(256), 0, stream>>>(qkv, rpb);
        proj_gemm_bf16<<<dim3(49, 2, 8), dim3(256), 0, stream>>>(qkv, wpb, proj_b, out);
    } else {
        qkv_gemm_kernel<<<dim3(49, 12, 8), dim3(256), 0, stream>>>(x, qkv_w, qkv);
        attn_mfma<<<dim3(49, HEADS, BATCH), dim3(256), 0, stream>>>(qkv, rpb);
        proj_gemm_kernel<<<dim3(49, 4, 8), dim3(256), 0, stream>>>(qkv, proj_w, proj_b, out);
    }
}

// Round 16
// 242.011 us; speedup vs baseline: 1.1737x; 1.0213x over previous
//
#include <hip/hip_runtime.h>

// NeighborhoodAttention2D: B=8, C=512, H=W=56, heads=16, d=32, KSZ=7
// Round 24: revert proj to r20 64x128 (64x256 retile was neutral-negative;
// best total remains r20's 244.0us). ONE new change: qkv BK 32->64.
//  Mechanism: r20 counters imply ~290cyc fixed overhead per K-step vs ~75cyc
//  MFMA; halving steps (16->8) halves barrier pairs while doubling MFMA/step.
//  LDS 40->80KB dbuf = 2 blocks/CU — which is what occupancy already measures,
//  so nothing is lost (m132's BK=128 regression was a 3->2 drop; ours is 2->2).
//  Pitch 64 elems = 128B (rows bank-aligned) => new swizzle: store chunk
//  q^(row&7); frag read ((kk*4+quad)^(l15&7))*8 -> 2-way (free). vmcnt(10).
// attn/prep/proj/fallbacks = r20 exact.

typedef unsigned short ushort_t;
typedef short bf16x8 __attribute__((ext_vector_type(8)));      // 8 bf16 = 4 VGPRs
typedef short bf16x4 __attribute__((ext_vector_type(4)));      // 4 bf16 = 2 VGPRs
typedef float f32x4 __attribute__((ext_vector_type(4)));       // MFMA C/D frag
typedef unsigned int uint4_t __attribute__((ext_vector_type(4)));
typedef unsigned int uint2_t __attribute__((ext_vector_type(2)));

#define BATCH 8
#define HEADS 16
#define HW 3136
#define HH 56
#define DD 32
#define CC 512
#define PLANE ((size_t)BATCH * HEADS * HW * DD)   // 12,845,056 elems (= B*C*HW)
#define OUT_TOT ((size_t)BATCH * CC * HW)
#define LP 40                                      // fallback-GEMM LDS pitch
#define LPG 32                                     // proj gload_lds pitch (BK=32)
#define LPQ 64                                     // qkv gload_lds pitch (BK=64)

// attention tile geometry
#define KT 14
#define KP 32
#define VPP 228

#define WQ_ELEMS (1536 * 512)
#define WP_ELEMS (512 * 512)

__device__ __forceinline__ ushort_t f2bf(float f) {
    union { float f; unsigned int i; } v; v.f = f;
    unsigned int r = v.i + 0x7FFFu + ((v.i >> 16) & 1u);   // RNE
    return (ushort_t)(r >> 16);
}
__device__ __forceinline__ unsigned int pack2(float a, float b) {
    return (unsigned int)f2bf(a) | ((unsigned int)f2bf(b) << 16);
}

__device__ __forceinline__ f32x4 mfma16x16x16(bf16x4 a, bf16x4 b, f32x4 c) {
#if __has_builtin(__builtin_amdgcn_mfma_f32_16x16x16bf16_1k)
    return __builtin_amdgcn_mfma_f32_16x16x16bf16_1k(a, b, c, 0, 0, 0);
#else
    f32x4 d;
    asm("v_mfma_f32_16x16x16_bf16 %0, %1, %2, %3" : "=v"(d) : "v"(a), "v"(b), "v"(c));
    return d;
#endif
}

// async global->LDS, 16B per lane; lds dest must be wave-linear (base + lane*16)
__device__ __forceinline__ void gload16(const ushort_t* g, ushort_t* l) {
    __builtin_amdgcn_global_load_lds(
        (const __attribute__((address_space(1))) unsigned int*)g,
        (__attribute__((address_space(3))) unsigned int*)l, 16, 0, 0);
}

__global__ __launch_bounds__(256) void zero_out_f32(float* __restrict__ out) {
    size_t idx = (size_t)blockIdx.x * 256 + threadIdx.x;
    if (idx < OUT_TOT) out[idx] = 0.f;
}

// ---------------- prep: both weight matrices f32 -> bf16, one launch ----------------
__global__ __launch_bounds__(256) void cvt_weights(const float* __restrict__ wa,
                                                   ushort_t* __restrict__ da, int n8a,
                                                   const float* __restrict__ wb,
                                                   ushort_t* __restrict__ db, int n8b) {
    int idx = blockIdx.x * 256 + threadIdx.x;
    const float* s;
    ushort_t* d;
    int i;
    if (idx < n8a) {
        s = wa; d = da; i = idx;
    } else {
        i = idx - n8a;
        if (i >= n8b) return;
        s = wb; d = db;
    }
    const float4* sp = (const float4*)s + (size_t)i * 2;
    float4 f0 = sp[0], f1 = sp[1];
    uint4_t u;
    u[0] = pack2(f0.x, f0.y);
    u[1] = pack2(f0.z, f0.w);
    u[2] = pack2(f1.x, f1.y);
    u[3] = pack2(f1.z, f1.w);
    *(uint4_t*)(d + (size_t)i * 8) = u;
}

// ---------------- prep: x [b][c][hw] f32 -> xbf [b][hw][c] bf16 ----------------
__global__ __launch_bounds__(256) void xpose_cvt(const float* __restrict__ x,
                                                 ushort_t* __restrict__ xb) {
    __shared__ ushort_t T[64 * 64];                // 8192 B
    int tid = threadIdx.x;
    int hw0 = blockIdx.x * 64;
    int c0 = blockIdx.y * 64;
    int b = blockIdx.z;

    int cr = tid >> 2, hq = tid & 3;
    const float* src = x + ((size_t)b * CC + c0 + cr) * HW + hw0 + hq * 16;
    float4 f0 = *(const float4*)(src);
    float4 f1 = *(const float4*)(src + 4);
    float4 f2 = *(const float4*)(src + 8);
    float4 f3 = *(const float4*)(src + 12);
    uint4_t u0, u1;
    u0[0] = pack2(f0.x, f0.y); u0[1] = pack2(f0.z, f0.w);
    u0[2] = pack2(f1.x, f1.y); u0[3] = pack2(f1.z, f1.w);
    u1[0] = pack2(f2.x, f2.y); u1[1] = pack2(f2.z, f2.w);
    u1[2] = pack2(f3.x, f3.y); u1[3] = pack2(f3.z, f3.w);
    int sw = ((cr >> 4) & 3) << 4;
    int col0 = (hq * 16) ^ sw;
    *(uint4_t*)&T[cr * 64 + col0] = u0;
    *(uint4_t*)&T[cr * 64 + col0 + 8] = u1;

    __syncthreads();

    int p = tid >> 2, cq = tid & 3;
    int pc = p ^ (cq << 4);
    unsigned vv[8];
    #pragma unroll
    for (int j = 0; j < 16; j += 2) {
        unsigned a = T[(cq * 16 + j) * 64 + pc];
        unsigned b2 = T[(cq * 16 + j + 1) * 64 + pc];
        vv[j >> 1] = a | (b2 << 16);
    }
    ushort_t* dst = xb + ((size_t)b * HW + hw0 + p) * CC + c0 + cq * 16;
    uint4_t w0, w1;
    w0[0] = vv[0]; w0[1] = vv[1]; w0[2] = vv[2]; w0[3] = vv[3];
    w1[0] = vv[4]; w1[1] = vv[5]; w1[2] = vv[6]; w1[3] = vv[7];
    *(uint4_t*)&dst[0] = w0;
    *(uint4_t*)&dst[8] = w1;
}

// ---------------- GEMM1 (bf16): qkv^T = wq (1536x512) . xb ([b][hw][c]) ----------
// 256n x 64px tile, BK=64 (8 K-steps), dbuf + counted vmcnt(10), XCD swizzle.
__global__ __launch_bounds__(256) void qkv_gemm_bf16(const ushort_t* __restrict__ xb,
                                                     const ushort_t* __restrict__ w,
                                                     ushort_t* __restrict__ qkv) {
    __shared__ __align__(16) ushort_t lds_p[2][256 * LPQ];   // 2 x 32768 B
    __shared__ __align__(16) ushort_t lds_q[2][64 * LPQ];    // 2 x  8192 B
    int tid = threadIdx.x;

    // T1 XCD swizzle: grid 49x6x8 = 2352 = 8 x 294; each XCD chunk = one batch b
    int lid = ((int)blockIdx.z * 6 + (int)blockIdx.y) * 49 + (int)blockIdx.x;
    int wl = (lid & 7) * 294 + (lid >> 3);
    int p0 = (wl % 49) * 64;
    int rest = wl / 49;
    int n0 = (rest % 6) * 256;
    int b = rest / 6;

    int lane = tid & 63, wv = tid >> 6;
    int wp = wv & 1, wq = wv >> 1;
    int quad = lane >> 4, l15 = lane & 15;

    f32x4 acc[8][2];
    #pragma unroll
    for (int i = 0; i < 8; ++i)
        #pragma unroll
        for (int jq = 0; jq < 2; ++jq) acc[i][jq] = (f32x4){0.f, 0.f, 0.f, 0.f};

    int s7 = l15 & 7;                          // row&7 for all frag rows (16i+l15)

    // per-thread staging descriptors (constant across kt); 8-chunk rows
    int ca_row[8], ca_k8[8];
    #pragma unroll
    for (int r = 0; r < 8; ++r) {
        int c = r * 256 + tid;                 // A: 2048 chunks
        ca_row[r] = c >> 3;
        ca_k8[r] = ((c & 7) ^ ((c >> 3) & 7)) * 8;
    }
    int cb_row[2], cb_k8[2];
    #pragma unroll
    for (int r = 0; r < 2; ++r) {
        int c = r * 256 + tid;                 // B: 512 chunks
        cb_row[r] = c >> 3;
        cb_k8[r] = ((c & 7) ^ ((c >> 3) & 7)) * 8;
    }

    auto stage = [&](int buf, int ko) {
        #pragma unroll
        for (int r = 0; r < 8; ++r)
            gload16(w + (size_t)(n0 + ca_row[r]) * CC + ko + ca_k8[r],
                    &lds_p[buf][(r * 256 + tid) * 8]);
        #pragma unroll
        for (int r = 0; r < 2; ++r)
            gload16(xb + ((size_t)b * HW + p0 + cb_row[r]) * CC + ko + cb_k8[r],
                    &lds_q[buf][(r * 256 + tid) * 8]);
    };

    auto compute_tile = [&](int cur) {
        #pragma unroll
        for (int kk = 0; kk < 2; ++kk) {       // two 32-k slices of the 64-k tile
            int cha = ((kk * 4 + quad) ^ s7) * 8;
            bf16x8 afrag[8], bfrag[2];
            #pragma unroll
            for (int i = 0; i < 8; ++i)
                afrag[i] = *(const bf16x8*)&lds_p[cur][(wp * 128 + i * 16 + l15) * LPQ + cha];
            #pragma unroll
            for (int jq = 0; jq < 2; ++jq)
                bfrag[jq] = *(const bf16x8*)&lds_q[cur][(wq * 32 + jq * 16 + l15) * LPQ + cha];
            #pragma unroll
            for (int i = 0; i < 8; ++i)
                #pragma unroll
                for (int jq = 0; jq < 2; ++jq)
                    acc[i][jq] = __builtin_amdgcn_mfma_f32_16x16x32_bf16(afrag[i], bfrag[jq],
                                                                         acc[i][jq], 0, 0, 0);
        }
    };

    const int NKT = CC / 64;                   // 8
    // prologue: stage tile 0 into buffer 0, full drain once
    stage(0, 0);
    asm volatile("s_waitcnt vmcnt(0)" ::: "memory");
    __builtin_amdgcn_s_barrier();
    asm volatile("" ::: "memory");

    for (int kt = 0; kt < NKT - 1; ++kt) {
        int cur = kt & 1;
        stage(cur ^ 1, (kt + 1) * 64);
        // counted wait for tile kt's 10 loads (oldest); kt+1's 10 stay in flight
        asm volatile("s_waitcnt vmcnt(10)" ::: "memory");
        __builtin_amdgcn_s_barrier();
        asm volatile("" ::: "memory");
        compute_tile(cur);
        asm volatile("" ::: "memory");
        __builtin_amdgcn_s_barrier();          // readers of buf[cur] done before next staging
        asm volatile("" ::: "memory");
    }
    asm volatile("s_waitcnt vmcnt(0)" ::: "memory");
    __builtin_amdgcn_s_barrier();
    asm volatile("" ::: "memory");
    compute_tile((NKT - 1) & 1);

    const float qscale = 0.17677669529663687f;   // 1/sqrt(32)
    #pragma unroll
    for (int i = 0; i < 8; ++i) {
        int nbase = n0 + wp * 128 + i * 16 + quad * 4;
        int which = nbase >> 9;
        int h = (nbase >> 5) & 15;
        int dch = nbase & 31;
        float sc = (which == 0) ? qscale : 1.0f;
        #pragma unroll
        for (int jq = 0; jq < 2; ++jq) {
            int pix = p0 + wq * 32 + jq * 16 + l15;
            uint2_t v;
            v[0] = pack2(acc[i][jq][0] * sc, acc[i][jq][1] * sc);
            v[1] = pack2(acc[i][jq][2] * sc, acc[i][jq][3] * sc);
            ushort_t* dst = qkv + (size_t)which * PLANE +
                            ((((size_t)b * HEADS + h) * HW + pix) * DD + dch);
            *(uint2_t*)dst = v;
        }
    }
}

// ---------------- GEMM1 fallback (f32 inputs) ----------------
__global__ __launch_bounds__(256) void qkv_gemm_kernel(const float* __restrict__ x,
                                                       const float* __restrict__ w,
                                                       ushort_t* __restrict__ qkv) {
    __shared__ __align__(16) ushort_t lds_p[128 * LP];
    __shared__ __align__(16) ushort_t lds_q[64 * LP];
    const int K = CC;
    int tid = threadIdx.x;
    int b = blockIdx.z;
    int n0 = blockIdx.y * 128;
    int p0 = blockIdx.x * 64;
    int lane = tid & 63, wv = tid >> 6;
    int wp = wv & 1, wq = wv >> 1;
    int quad = lane >> 4, l15 = lane & 15;

    f32x4 acc[4][2];
    #pragma unroll
    for (int i = 0; i < 4; ++i)
        #pragma unroll
        for (int jq = 0; jq < 2; ++jq) acc[i][jq] = (f32x4){0.f, 0.f, 0.f, 0.f};

    int spx = tid & 63;
    int sk8 = (tid >> 6) * 8;

    for (int kt = 0; kt < K / 32; ++kt) {
        __syncthreads();
        #pragma unroll
        for (int r = 0; r < 2; ++r) {
            int chunk = tid + r * 256;
            int row = chunk >> 2, k8 = (chunk & 3) * 8;
            const float* src = w + (size_t)(n0 + row) * K + kt * 32 + k8;
            float4 f0 = *(const float4*)src;
            float4 f1 = *(const float4*)(src + 4);
            uint4_t u;
            u[0] = pack2(f0.x, f0.y);
            u[1] = pack2(f0.z, f0.w);
            u[2] = pack2(f1.x, f1.y);
            u[3] = pack2(f1.z, f1.w);
            *(uint4_t*)&lds_p[row * LP + k8] = u;
        }
        {
            const float* xcol = x + ((size_t)b * CC + kt * 32 + sk8) * HW + p0 + spx;
            float v0 = xcol[0];
            float v1 = xcol[(size_t)HW];
            float v2 = xcol[(size_t)2 * HW];
            float v3 = xcol[(size_t)3 * HW];
            float v4 = xcol[(size_t)4 * HW];
            float v5 = xcol[(size_t)5 * HW];
            float v6 = xcol[(size_t)6 * HW];
            float v7 = xcol[(size_t)7 * HW];
            uint4_t u;
            u[0] = pack2(v0, v1);
            u[1] = pack2(v2, v3);
            u[2] = pack2(v4, v5);
            u[3] = pack2(v6, v7);
            *(uint4_t*)&lds_q[spx * LP + sk8] = u;
        }
        __syncthreads();
        bf16x8 afrag[4], bfrag[2];
        #pragma unroll
        for (int i = 0; i < 4; ++i)
            afrag[i] = *(const bf16x8*)&lds_p[(wp * 64 + i * 16 + l15) * LP + quad * 8];
        #pragma unroll
        for (int jq = 0; jq < 2; ++jq)
            bfrag[jq] = *(const bf16x8*)&lds_q[(wq * 32 + jq * 16 + l15) * LP + quad * 8];
        #pragma unroll
        for (int i = 0; i < 4; ++i)
            #pragma unroll
            for (int jq = 0; jq < 2; ++jq)
                acc[i][jq] = __builtin_amdgcn_mfma_f32_16x16x32_bf16(afrag[i], bfrag[jq],
                                                                     acc[i][jq], 0, 0, 0);
    }
    const float qscale = 0.17677669529663687f;
    #pragma unroll
    for (int i = 0; i < 4; ++i) {
        int nbase = n0 + wp * 64 + i * 16 + quad * 4;
        int which = nbase >> 9;
        int h = (nbase >> 5) & 15;
        int dch = nbase & 31;
        float sc = (which == 0) ? qscale : 1.0f;
        #pragma unroll
        for (int jq = 0; jq < 2; ++jq) {
            int pix = p0 + wq * 32 + jq * 16 + l15;
            uint2_t v;
            v[0] = pack2(acc[i][jq][0] * sc, acc[i][jq][1] * sc);
            v[1] = pack2(acc[i][jq][2] * sc, acc[i][jq][3] * sc);
            ushort_t* dst = qkv + (size_t)which * PLANE +
                            ((((size_t)b * HEADS + h) * HW + pix) * DD + dch);
            *(uint2_t*)dst = v;
        }
    }
}

// ---------------- MFMA attention: one block per (b, h, 8x8 query tile) ----------------
__global__ __launch_bounds__(256, 4) void attn_mfma(ushort_t* __restrict__ qkv,
                                                    const float* __restrict__ rpb) {
    __shared__ __align__(16) ushort_t Klds[224 * KP];        // 14336 B, [kk][d]
    __shared__ __align__(16) ushort_t Vlds[DD * VPP];        // 14592 B, [d][kk]
    __shared__ float rpbl[169];                              //   676 B

    int tid = threadIdx.x;

    // T1 XCD swizzle: grid 49x16x8 = 6272 = 8 x 784; each XCD chunk = one batch b
    int lid = ((int)blockIdx.z * 16 + (int)blockIdx.y) * 49 + (int)blockIdx.x;
    int wl = (lid & 7) * 784 + (lid >> 3);
    int tile = wl % 49;
    int rest = wl / 49;
    int h = rest % 16;
    int b = rest / 16;

    int ti = tile / 7, tj = tile - ti * 7;
    int i0 = ti * 8, j0 = tj * 8;
    int kr0 = min(max(i0 - 3, 0), HH - 14);
    int kc0 = min(max(j0 - 3, 0), HH - 14);

    const ushort_t* qp = qkv + (((size_t)b * HEADS + h) * HW) * DD;
    const ushort_t* kp = qp + PLANE;
    const ushort_t* vp = qp + 2 * PLANE;

    if (tid < 169) rpbl[tid] = rpb[h * 169 + tid];

    #pragma unroll
    for (int r = 0; r < 4; ++r) {
        int idx = tid + r * 256;
        if (idx < 784) {
            int u = idx / 56;
            int rem = idx - u * 56;
            int w = rem >> 2, d8 = (rem & 3) << 3;
            const ushort_t* src = kp + ((size_t)((kr0 + u) * HH + kc0 + w)) * DD + d8;
            *(uint4_t*)&Klds[(u * 16 + w) * KP + d8] = *(const uint4_t*)src;
        } else if (idx < 896) {
            int z = idx - 784;
            int u = z >> 3, rem = z & 7;
            int w = 14 + (rem >> 2), d8 = (rem & 3) << 3;
            *(uint4_t*)&Klds[(u * 16 + w) * KP + d8] = (uint4_t){0, 0, 0, 0};
        }
    }
    #pragma unroll
    for (int rr = 0; rr < 2; ++rr) {
        int idx = tid + rr * 256;
        if (idx < 448) {
            int u = idx >> 5, rem = idx & 31;
            int pr = rem >> 2, d8 = (rem & 3) << 3;
            int kk0 = u * 16 + pr * 2;
            if (pr < 7) {
                const ushort_t* s0 = vp + ((size_t)((kr0 + u) * HH + kc0 + pr * 2)) * DD + d8;
                uint4_t a = *(const uint4_t*)s0;
                uint4_t c = *(const uint4_t*)(s0 + DD);
                #pragma unroll
                for (int e = 0; e < 4; ++e) {
                    unsigned lo = (a[e] & 0xFFFFu) | (c[e] << 16);
                    unsigned hi = (a[e] >> 16) | (c[e] & 0xFFFF0000u);
                    *(unsigned*)&Vlds[(d8 + 2 * e) * VPP + kk0] = lo;
                    *(unsigned*)&Vlds[(d8 + 2 * e + 1) * VPP + kk0] = hi;
                }
            } else {
                #pragma unroll
                for (int e = 0; e < 8; ++e)
                    *(unsigned*)&Vlds[(d8 + e) * VPP + kk0] = 0;
            }
        }
    }

    int lane = tid & 63, wv = tid >> 6;
    int l15 = lane & 15, quad = lane >> 4;
    int q_idx = wv * 16 + l15;
    int qi = i0 + (q_idx >> 3), qj = j0 + (q_idx & 7);
    int si = min(max(qi - 3, 0), HH - 7);
    int sj = min(max(qj - 3, 0), HH - 7);

    bf16x8 bq = *(const bf16x8*)(qp + ((size_t)(qi * HH + qj)) * DD + quad * 8);

    int jbase = kc0 + quad * 4 - sj;
    int cbase = kc0 + quad * 4 - qj + 6;
    int coff[4];
    bool cok[4];
    #pragma unroll
    for (int r2 = 0; r2 < 4; ++r2) {
        cok[r2] = (unsigned)(jbase + r2) <= 6u;
        coff[r2] = min(max(cbase + r2, 0), 12);
    }

    __syncthreads();

    f32x4 lg[KT];
    f32x4 zf = {0.f, 0.f, 0.f, 0.f};
    __builtin_amdgcn_s_setprio(1);             // T5: QK^T cluster
    #pragma unroll
    for (int t = 0; t < KT; ++t) {
        bf16x8 ak = *(const bf16x8*)&Klds[(t * 16 + l15) * KP + quad * 8];
        lg[t] = __builtin_amdgcn_mfma_f32_16x16x32_bf16(ak, bq, zf, 0, 0, 0);
    }
    __builtin_amdgcn_s_setprio(0);

    int abase = kr0 - qi + 6;
    #pragma unroll
    for (int t = 0; t < KT; ++t) {
        bool rok = (unsigned)(kr0 + t - si) <= 6u;
        int arow = min(max(abase + t, 0), 12);
        const float* br = &rpbl[arow * 13];
        #pragma unroll
        for (int r2 = 0; r2 < 4; ++r2) {
            float bias = br[coff[r2]];
            lg[t][r2] = (rok && cok[r2]) ? lg[t][r2] + bias : -1e30f;
        }
    }

    float m = -1e30f;
    #pragma unroll
    for (int t = 0; t < KT; ++t)
        #pragma unroll
        for (int r2 = 0; r2 < 4; ++r2) m = fmaxf(m, lg[t][r2]);
    m = fmaxf(m, __shfl_xor(m, 16));
    m = fmaxf(m, __shfl_xor(m, 32));
    float s = 0.f;
    #pragma unroll
    for (int t = 0; t < KT; ++t)
        #pragma unroll
        for (int r2 = 0; r2 < 4; ++r2) {
            float e = __expf(lg[t][r2] - m);
            lg[t][r2] = e;
            s += e;
        }
    s += __shfl_xor(s, 16);
    s += __shfl_xor(s, 32);
    float inv = 1.f / s;

    bf16x4 pb[KT];
    #pragma unroll
    for (int t = 0; t < KT; ++t) {
        union { uint2_t u; bf16x4 v; } cv;
        cv.u[0] = pack2(lg[t][0], lg[t][1]);
        cv.u[1] = pack2(lg[t][2], lg[t][3]);
        pb[t] = cv.v;
    }

    f32x4 acc0 = zf, acc1 = zf;
    __builtin_amdgcn_s_setprio(1);             // T5: PV cluster
    #pragma unroll
    for (int t = 0; t < KT; ++t) {
        bf16x4 bv0 = *(const bf16x4*)&Vlds[l15 * VPP + t * 16 + quad * 4];
        bf16x4 bv1 = *(const bf16x4*)&Vlds[(16 + l15) * VPP + t * 16 + quad * 4];
        acc0 = mfma16x16x16(pb[t], bv0, acc0);
        acc1 = mfma16x16x16(pb[t], bv1, acc1);
    }
    __builtin_amdgcn_s_setprio(0);

    ushort_t* op = qkv + (((size_t)b * HEADS + h) * HW) * DD;
    #pragma unroll
    for (int e = 0; e < 4; ++e) {
        float invq = __shfl(inv, quad * 4 + e);
        int q2 = wv * 16 + quad * 4 + e;
        int pix = (i0 + (q2 >> 3)) * HH + j0 + (q2 & 7);
        op[(size_t)pix * DD + l15] = f2bf(acc0[e] * invq);
        op[(size_t)pix * DD + 16 + l15] = f2bf(acc1[e] * invq);
    }
}

// ---------------- GEMM3 (bf16): y = attn_out . wpb^T + b; OUT f32 (r20 exact) ----
__global__ __launch_bounds__(256) void proj_gemm_bf16(const ushort_t* __restrict__ ao,
                                                      const ushort_t* __restrict__ w,
                                                      const float* __restrict__ bias,
                                                      float* __restrict__ out) {
    __shared__ __align__(16) ushort_t lds_p[2][64 * LPG];    // 2 x 4096 B
    __shared__ __align__(16) ushort_t lds_q[2][128 * LPG];   // 2 x 8192 B
    int tid = threadIdx.x;

    // T1 XCD swizzle: grid 49x4x8 = 1568 = 8 x 196; each XCD chunk = one batch b
    int lid = ((int)blockIdx.z * 4 + (int)blockIdx.y) * 49 + (int)blockIdx.x;
    int wl = (lid & 7) * 196 + (lid >> 3);
    int p0 = (wl % 49) * 64;
    int rest = wl / 49;
    int c0 = (rest % 4) * 128;
    int b = rest / 4;

    int lane = tid & 63, wv = tid >> 6;
    int wp = wv & 1, wq = wv >> 1;
    int quad = lane >> 4, l15 = lane & 15;

    f32x4 acc[2][4];
    #pragma unroll
    for (int i = 0; i < 2; ++i)
        #pragma unroll
        for (int jq = 0; jq < 4; ++jq) acc[i][jq] = (f32x4){0.f, 0.f, 0.f, 0.f};

    const ushort_t* abase = ao + ((size_t)b * HEADS) * HW * DD;
    int swz = (l15 >> 1) & 3;
    int cha = (quad ^ swz) * 8;

    int ca_row = tid >> 2;
    int ca_k8 = ((tid & 3) ^ ((tid >> 3) & 3)) * 8;
    int cb_row[2], cb_k8[2];
    #pragma unroll
    for (int r = 0; r < 2; ++r) {
        int c = r * 256 + tid;
        cb_row[r] = c >> 2;
        cb_k8[r] = ((c & 3) ^ ((c >> 3) & 3)) * 8;
    }

    auto compute_tile = [&](int cur) {
        bf16x8 afrag[2], bfrag[4];
        #pragma unroll
        for (int i = 0; i < 2; ++i)
            afrag[i] = *(const bf16x8*)&lds_p[cur][(wp * 32 + i * 16 + l15) * LPG + cha];
        #pragma unroll
        for (int jq = 0; jq < 4; ++jq)
            bfrag[jq] = *(const bf16x8*)&lds_q[cur][(wq * 64 + jq * 16 + l15) * LPG + cha];
        #pragma unroll
        for (int i = 0; i < 2; ++i)
            #pragma unroll
            for (int jq = 0; jq < 4; ++jq)
                acc[i][jq] = __builtin_amdgcn_mfma_f32_16x16x32_bf16(afrag[i], bfrag[jq],
                                                                     acc[i][jq], 0, 0, 0);
    };

    const int NKT = CC / 32;
    // prologue: stage tile 0 into buffer 0 (A k-tile 0 = head 0), full drain once
    gload16(abase + ((size_t)0 * HW + p0 + ca_row) * DD + ca_k8, &lds_p[0][tid * 8]);
    #pragma unroll
    for (int r = 0; r < 2; ++r)
        gload16(w + (size_t)(c0 + cb_row[r]) * CC + cb_k8[r],
                &lds_q[0][(r * 256 + tid) * 8]);
    asm volatile("s_waitcnt vmcnt(0)" ::: "memory");
    __builtin_amdgcn_s_barrier();
    asm volatile("" ::: "memory");

    for (int kt = 0; kt < NKT - 1; ++kt) {
        int cur = kt & 1;
        int kn = kt + 1;
        gload16(abase + ((size_t)kn * HW + p0 + ca_row) * DD + ca_k8,
                &lds_p[cur ^ 1][tid * 8]);
        #pragma unroll
        for (int r = 0; r < 2; ++r)
            gload16(w + (size_t)(c0 + cb_row[r]) * CC + kn * 32 + cb_k8[r],
                    &lds_q[cur ^ 1][(r * 256 + tid) * 8]);
        // T4: wait ONLY for tile kt's 3 loads; kt+1's 3 stay in flight
        asm volatile("s_waitcnt vmcnt(3)" ::: "memory");
        __builtin_amdgcn_s_barrier();
        asm volatile("" ::: "memory");
        compute_tile(cur);
        asm volatile("" ::: "memory");
        __builtin_amdgcn_s_barrier();
        asm volatile("" ::: "memory");
    }
    asm volatile("s_waitcnt vmcnt(0)" ::: "memory");
    __builtin_amdgcn_s_barrier();
    asm volatile("" ::: "memory");
    compute_tile((NKT - 1) & 1);

    #pragma unroll
    for (int i = 0; i < 2; ++i) {
        int pix = p0 + wp * 32 + i * 16 + quad * 4;
        #pragma unroll
        for (int jq = 0; jq < 4; ++jq) {
            int cch = c0 + wq * 64 + jq * 16 + l15;
            float bz = bias[cch];
            float4 v;
            v.x = acc[i][jq][0] + bz;
            v.y = acc[i][jq][1] + bz;
            v.z = acc[i][jq][2] + bz;
            v.w = acc[i][jq][3] + bz;
            float* dst = out + ((size_t)b * CC + cch) * HW + pix;
            *(float4*)dst = v;
        }
    }
}

// ---------------- GEMM3 fallback (f32 w) ----------------
__global__ __launch_bounds__(256) void proj_gemm_kernel(const ushort_t* __restrict__ ao,
                                                        const float* __restrict__ w,
                                                        const float* __restrict__ bias,
                                                        float* __restrict__ out) {
    __shared__ __align__(16) ushort_t lds_p[64 * LP];
    __shared__ __align__(16) ushort_t lds_q[128 * LP];
    const int K = CC;
    int tid = threadIdx.x;
    int b = blockIdx.z;
    int p0 = blockIdx.x * 64;
    int c0 = blockIdx.y * 128;
    int lane = tid & 63, wv = tid >> 6;
    int wp = wv & 1, wq = wv >> 1;
    int quad = lane >> 4, l15 = lane & 15;

    f32x4 acc[2][4];
    #pragma unroll
    for (int i = 0; i < 2; ++i)
        #pragma unroll
        for (int jq = 0; jq < 4; ++jq) acc[i][jq] = (f32x4){0.f, 0.f, 0.f, 0.f};

    const ushort_t* abase = ao + ((size_t)b * HEADS) * HW * DD;

    for (int kt = 0; kt < K / 32; ++kt) {
        __syncthreads();
        {
            int row = tid >> 2, k8 = (tid & 3) * 8;
            uint4_t u = *(const uint4_t*)(abase + ((size_t)kt * HW + p0 + row) * DD + k8);
            *(uint4_t*)&lds_p[row * LP + k8] = u;
        }
        #pragma unroll
        for (int r = 0; r < 2; ++r) {
            int chunk = tid + r * 256;
            int row = chunk >> 2, k8 = (chunk & 3) * 8;
            const float* src = w + (size_t)(c0 + row) * K + kt * 32 + k8;
            float4 f0 = *(const float4*)src;
            float4 f1 = *(const float4*)(src + 4);
            uint4_t u;
            u[0] = pack2(f0.x, f0.y);
            u[1] = pack2(f0.z, f0.w);
            u[2] = pack2(f1.x, f1.y);
            u[3] = pack2(f1.z, f1.w);
            *(uint4_t*)&lds_q[row * LP + k8] = u;
        }
        __syncthreads();
        bf16x8 afrag[2], bfrag[4];
        #pragma unroll
        for (int i = 0; i < 2; ++i)
            afrag[i] = *(const bf16x8*)&lds_p[(wp * 32 + i * 16 + l15) * LP + quad * 8];
        #pragma unroll
        for (int jq = 0; jq < 4; ++jq)
            bfrag[jq] = *(const bf16x8*)&lds_q[(wq * 64 + jq * 16 + l15) * LP + quad * 8];
        #pragma unroll
        for (int i = 0; i < 2; ++i)
            #pragma unroll
            for (int jq = 0; jq < 4; ++jq)
                acc[i][jq] = __builtin_amdgcn_mfma_f32_16x16x32_bf16(afrag[i], bfrag[jq],
                                                                     acc[i][jq], 0, 0, 0);
    }
    #pragma unroll
    for (int i = 0; i < 2; ++i) {
        int pix = p0 + wp * 32 + i * 16 + quad * 4;
        #pragma unroll
        for (int jq = 0; jq < 4; ++jq) {
            int cch = c0 + wq * 64 + jq * 16 + l15;
            float bz = bias[cch];
            float4 v;
            v.x = acc[i][jq][0] + bz;
            v.y = acc[i][jq][1] + bz;
            v.z = acc[i][jq][2] + bz;
            v.w = acc[i][jq][3] + bz;
            float* dst = out + ((size_t)b * CC + cch) * HW + pix;
            *(float4*)dst = v;
        }
    }
}

extern "C" void kernel_launch(void* const* d_in, const int* in_sizes, int n_in,
                              void* d_out, int out_size, void* d_ws, size_t ws_size,
                              hipStream_t stream) {
    const float* x = (const float*)d_in[0];
    const float* qkv_w = (const float*)d_in[1];
    const float* rpb = (const float*)d_in[2];
    const float* proj_w = (const float*)d_in[3];
    const float* proj_b = (const float*)d_in[4];
    float* out = (float*)d_out;

    size_t need_min = 3 * PLANE * sizeof(ushort_t);                       // 73.5 MB
    size_t need_full = (4 * PLANE + WQ_ELEMS + WP_ELEMS) * sizeof(ushort_t);  // 100 MB

    if (ws_size < need_min) {
        zero_out_f32<<<dim3((int)((OUT_TOT + 255) / 256)), dim3(256), 0, stream>>>(out);
        return;
    }

    ushort_t* qkv = (ushort_t*)d_ws;                 // q/k/v: 3 bf16 planes

    if (ws_size >= need_full) {
        ushort_t* xbf = qkv + 3 * PLANE;             // bf16 x, [b][hw][c] (TRANSPOSED)
        ushort_t* wqb = qkv + 4 * PLANE;             // bf16 qkv_w
        ushort_t* wpb = wqb + WQ_ELEMS;              // bf16 proj_w

        xpose_cvt<<<dim3(49, 8, 8), dim3(256), 0, stream>>>(x, xbf);
        cvt_weights<<<dim3((WQ_ELEMS / 8 + WP_ELEMS / 8 + 255) / 256), dim3(256), 0,
                      stream>>>(qkv_w, wqb, WQ_ELEMS / 8, proj_w, wpb, WP_ELEMS / 8);

        qkv_gemm_bf16<<<dim3(49, 6, 8), dim3(256), 0, stream>>>(xbf, wqb, qkv);
        attn_mfma<<<dim3(49, HEADS, BATCH), dim3(256), 0, stream>>>(qkv, rpb);
        proj_gemm_bf16<<<dim3(49, 4, 8), dim3(256), 0, stream>>>(qkv, wpb, proj_b, out);
    } else {
        qkv_gemm_kernel<<<dim3(49, 12, 8), dim3(256), 0, stream>>>(x, qkv_w, qkv);
        attn_mfma<<<dim3(49, HEADS, BATCH), dim3(256), 0, stream>>>(qkv, rpb);
        proj_gemm_kernel<<<dim3(49, 4, 8), dim3(256), 0, stream>>>(qkv, proj_w, proj_b, out);
    }
}

// Round 17
// 241.038 us; speedup vs baseline: 1.1785x; 1.0040x over previous
//
#include <hip/hip_runtime.h>

// NeighborhoodAttention2D: B=8, C=512, H=W=56, heads=16, d=32, KSZ=7
// Round 25: BK=64 VALIDATED on qkv (71.5->64.3us, total 242.0 best).
// Apply the identical transformation to proj_gemm (the last 16-step/8-MFMA
// kernel): BK 32->64 => 8 K-steps x 16 MFMA/step, LDS 24.5->49KB dbuf
// (3 blk/CU), 6 loads/thread/tile -> vmcnt(6). Same validated swizzle
// involution (store octet (c&7)^(row&7); read ((kk*4+quad)^(l15&7))*8).
// qkv (BK=64), attn, prep, fallbacks byte-identical to green r24.

typedef unsigned short ushort_t;
typedef short bf16x8 __attribute__((ext_vector_type(8)));      // 8 bf16 = 4 VGPRs
typedef short bf16x4 __attribute__((ext_vector_type(4)));      // 4 bf16 = 2 VGPRs
typedef float f32x4 __attribute__((ext_vector_type(4)));       // MFMA C/D frag
typedef unsigned int uint4_t __attribute__((ext_vector_type(4)));
typedef unsigned int uint2_t __attribute__((ext_vector_type(2)));

#define BATCH 8
#define HEADS 16
#define HW 3136
#define HH 56
#define DD 32
#define CC 512
#define PLANE ((size_t)BATCH * HEADS * HW * DD)   // 12,845,056 elems (= B*C*HW)
#define OUT_TOT ((size_t)BATCH * CC * HW)
#define LP 40                                      // fallback-GEMM LDS pitch
#define LPQ 64                                     // BK=64 gload_lds pitch

// attention tile geometry
#define KT 14
#define KP 32
#define VPP 228

#define WQ_ELEMS (1536 * 512)
#define WP_ELEMS (512 * 512)

__device__ __forceinline__ ushort_t f2bf(float f) {
    union { float f; unsigned int i; } v; v.f = f;
    unsigned int r = v.i + 0x7FFFu + ((v.i >> 16) & 1u);   // RNE
    return (ushort_t)(r >> 16);
}
__device__ __forceinline__ unsigned int pack2(float a, float b) {
    return (unsigned int)f2bf(a) | ((unsigned int)f2bf(b) << 16);
}

__device__ __forceinline__ f32x4 mfma16x16x16(bf16x4 a, bf16x4 b, f32x4 c) {
#if __has_builtin(__builtin_amdgcn_mfma_f32_16x16x16bf16_1k)
    return __builtin_amdgcn_mfma_f32_16x16x16bf16_1k(a, b, c, 0, 0, 0);
#else
    f32x4 d;
    asm("v_mfma_f32_16x16x16_bf16 %0, %1, %2, %3" : "=v"(d) : "v"(a), "v"(b), "v"(c));
    return d;
#endif
}

// async global->LDS, 16B per lane; lds dest must be wave-linear (base + lane*16)
__device__ __forceinline__ void gload16(const ushort_t* g, ushort_t* l) {
    __builtin_amdgcn_global_load_lds(
        (const __attribute__((address_space(1))) unsigned int*)g,
        (__attribute__((address_space(3))) unsigned int*)l, 16, 0, 0);
}

__global__ __launch_bounds__(256) void zero_out_f32(float* __restrict__ out) {
    size_t idx = (size_t)blockIdx.x * 256 + threadIdx.x;
    if (idx < OUT_TOT) out[idx] = 0.f;
}

// ---------------- prep: both weight matrices f32 -> bf16, one launch ----------------
__global__ __launch_bounds__(256) void cvt_weights(const float* __restrict__ wa,
                                                   ushort_t* __restrict__ da, int n8a,
                                                   const float* __restrict__ wb,
                                                   ushort_t* __restrict__ db, int n8b) {
    int idx = blockIdx.x * 256 + threadIdx.x;
    const float* s;
    ushort_t* d;
    int i;
    if (idx < n8a) {
        s = wa; d = da; i = idx;
    } else {
        i = idx - n8a;
        if (i >= n8b) return;
        s = wb; d = db;
    }
    const float4* sp = (const float4*)s + (size_t)i * 2;
    float4 f0 = sp[0], f1 = sp[1];
    uint4_t u;
    u[0] = pack2(f0.x, f0.y);
    u[1] = pack2(f0.z, f0.w);
    u[2] = pack2(f1.x, f1.y);
    u[3] = pack2(f1.z, f1.w);
    *(uint4_t*)(d + (size_t)i * 8) = u;
}

// ---------------- prep: x [b][c][hw] f32 -> xbf [b][hw][c] bf16 ----------------
__global__ __launch_bounds__(256) void xpose_cvt(const float* __restrict__ x,
                                                 ushort_t* __restrict__ xb) {
    __shared__ ushort_t T[64 * 64];                // 8192 B
    int tid = threadIdx.x;
    int hw0 = blockIdx.x * 64;
    int c0 = blockIdx.y * 64;
    int b = blockIdx.z;

    int cr = tid >> 2, hq = tid & 3;
    const float* src = x + ((size_t)b * CC + c0 + cr) * HW + hw0 + hq * 16;
    float4 f0 = *(const float4*)(src);
    float4 f1 = *(const float4*)(src + 4);
    float4 f2 = *(const float4*)(src + 8);
    float4 f3 = *(const float4*)(src + 12);
    uint4_t u0, u1;
    u0[0] = pack2(f0.x, f0.y); u0[1] = pack2(f0.z, f0.w);
    u0[2] = pack2(f1.x, f1.y); u0[3] = pack2(f1.z, f1.w);
    u1[0] = pack2(f2.x, f2.y); u1[1] = pack2(f2.z, f2.w);
    u1[2] = pack2(f3.x, f3.y); u1[3] = pack2(f3.z, f3.w);
    int sw = ((cr >> 4) & 3) << 4;
    int col0 = (hq * 16) ^ sw;
    *(uint4_t*)&T[cr * 64 + col0] = u0;
    *(uint4_t*)&T[cr * 64 + col0 + 8] = u1;

    __syncthreads();

    int p = tid >> 2, cq = tid & 3;
    int pc = p ^ (cq << 4);
    unsigned vv[8];
    #pragma unroll
    for (int j = 0; j < 16; j += 2) {
        unsigned a = T[(cq * 16 + j) * 64 + pc];
        unsigned b2 = T[(cq * 16 + j + 1) * 64 + pc];
        vv[j >> 1] = a | (b2 << 16);
    }
    ushort_t* dst = xb + ((size_t)b * HW + hw0 + p) * CC + c0 + cq * 16;
    uint4_t w0, w1;
    w0[0] = vv[0]; w0[1] = vv[1]; w0[2] = vv[2]; w0[3] = vv[3];
    w1[0] = vv[4]; w1[1] = vv[5]; w1[2] = vv[6]; w1[3] = vv[7];
    *(uint4_t*)&dst[0] = w0;
    *(uint4_t*)&dst[8] = w1;
}

// ---------------- GEMM1 (bf16): qkv^T = wq (1536x512) . xb ([b][hw][c]) ----------
// 256n x 64px tile, BK=64 (8 K-steps), dbuf + counted vmcnt(10), XCD swizzle.
__global__ __launch_bounds__(256) void qkv_gemm_bf16(const ushort_t* __restrict__ xb,
                                                     const ushort_t* __restrict__ w,
                                                     ushort_t* __restrict__ qkv) {
    __shared__ __align__(16) ushort_t lds_p[2][256 * LPQ];   // 2 x 32768 B
    __shared__ __align__(16) ushort_t lds_q[2][64 * LPQ];    // 2 x  8192 B
    int tid = threadIdx.x;

    // T1 XCD swizzle: grid 49x6x8 = 2352 = 8 x 294; each XCD chunk = one batch b
    int lid = ((int)blockIdx.z * 6 + (int)blockIdx.y) * 49 + (int)blockIdx.x;
    int wl = (lid & 7) * 294 + (lid >> 3);
    int p0 = (wl % 49) * 64;
    int rest = wl / 49;
    int n0 = (rest % 6) * 256;
    int b = rest / 6;

    int lane = tid & 63, wv = tid >> 6;
    int wp = wv & 1, wq = wv >> 1;
    int quad = lane >> 4, l15 = lane & 15;

    f32x4 acc[8][2];
    #pragma unroll
    for (int i = 0; i < 8; ++i)
        #pragma unroll
        for (int jq = 0; jq < 2; ++jq) acc[i][jq] = (f32x4){0.f, 0.f, 0.f, 0.f};

    int s7 = l15 & 7;                          // row&7 for all frag rows (16i+l15)

    // per-thread staging descriptors (constant across kt); 8-chunk rows
    int ca_row[8], ca_k8[8];
    #pragma unroll
    for (int r = 0; r < 8; ++r) {
        int c = r * 256 + tid;                 // A: 2048 chunks
        ca_row[r] = c >> 3;
        ca_k8[r] = ((c & 7) ^ ((c >> 3) & 7)) * 8;
    }
    int cb_row[2], cb_k8[2];
    #pragma unroll
    for (int r = 0; r < 2; ++r) {
        int c = r * 256 + tid;                 // B: 512 chunks
        cb_row[r] = c >> 3;
        cb_k8[r] = ((c & 7) ^ ((c >> 3) & 7)) * 8;
    }

    auto stage = [&](int buf, int ko) {
        #pragma unroll
        for (int r = 0; r < 8; ++r)
            gload16(w + (size_t)(n0 + ca_row[r]) * CC + ko + ca_k8[r],
                    &lds_p[buf][(r * 256 + tid) * 8]);
        #pragma unroll
        for (int r = 0; r < 2; ++r)
            gload16(xb + ((size_t)b * HW + p0 + cb_row[r]) * CC + ko + cb_k8[r],
                    &lds_q[buf][(r * 256 + tid) * 8]);
    };

    auto compute_tile = [&](int cur) {
        #pragma unroll
        for (int kk = 0; kk < 2; ++kk) {       // two 32-k slices of the 64-k tile
            int cha = ((kk * 4 + quad) ^ s7) * 8;
            bf16x8 afrag[8], bfrag[2];
            #pragma unroll
            for (int i = 0; i < 8; ++i)
                afrag[i] = *(const bf16x8*)&lds_p[cur][(wp * 128 + i * 16 + l15) * LPQ + cha];
            #pragma unroll
            for (int jq = 0; jq < 2; ++jq)
                bfrag[jq] = *(const bf16x8*)&lds_q[cur][(wq * 32 + jq * 16 + l15) * LPQ + cha];
            #pragma unroll
            for (int i = 0; i < 8; ++i)
                #pragma unroll
                for (int jq = 0; jq < 2; ++jq)
                    acc[i][jq] = __builtin_amdgcn_mfma_f32_16x16x32_bf16(afrag[i], bfrag[jq],
                                                                         acc[i][jq], 0, 0, 0);
        }
    };

    const int NKT = CC / 64;                   // 8
    // prologue: stage tile 0 into buffer 0, full drain once
    stage(0, 0);
    asm volatile("s_waitcnt vmcnt(0)" ::: "memory");
    __builtin_amdgcn_s_barrier();
    asm volatile("" ::: "memory");

    for (int kt = 0; kt < NKT - 1; ++kt) {
        int cur = kt & 1;
        stage(cur ^ 1, (kt + 1) * 64);
        // counted wait for tile kt's 10 loads (oldest); kt+1's 10 stay in flight
        asm volatile("s_waitcnt vmcnt(10)" ::: "memory");
        __builtin_amdgcn_s_barrier();
        asm volatile("" ::: "memory");
        compute_tile(cur);
        asm volatile("" ::: "memory");
        __builtin_amdgcn_s_barrier();          // readers of buf[cur] done before next staging
        asm volatile("" ::: "memory");
    }
    asm volatile("s_waitcnt vmcnt(0)" ::: "memory");
    __builtin_amdgcn_s_barrier();
    asm volatile("" ::: "memory");
    compute_tile((NKT - 1) & 1);

    const float qscale = 0.17677669529663687f;   // 1/sqrt(32)
    #pragma unroll
    for (int i = 0; i < 8; ++i) {
        int nbase = n0 + wp * 128 + i * 16 + quad * 4;
        int which = nbase >> 9;
        int h = (nbase >> 5) & 15;
        int dch = nbase & 31;
        float sc = (which == 0) ? qscale : 1.0f;
        #pragma unroll
        for (int jq = 0; jq < 2; ++jq) {
            int pix = p0 + wq * 32 + jq * 16 + l15;
            uint2_t v;
            v[0] = pack2(acc[i][jq][0] * sc, acc[i][jq][1] * sc);
            v[1] = pack2(acc[i][jq][2] * sc, acc[i][jq][3] * sc);
            ushort_t* dst = qkv + (size_t)which * PLANE +
                            ((((size_t)b * HEADS + h) * HW + pix) * DD + dch);
            *(uint2_t*)dst = v;
        }
    }
}

// ---------------- GEMM1 fallback (f32 inputs) ----------------
__global__ __launch_bounds__(256) void qkv_gemm_kernel(const float* __restrict__ x,
                                                       const float* __restrict__ w,
                                                       ushort_t* __restrict__ qkv) {
    __shared__ __align__(16) ushort_t lds_p[128 * LP];
    __shared__ __align__(16) ushort_t lds_q[64 * LP];
    const int K = CC;
    int tid = threadIdx.x;
    int b = blockIdx.z;
    int n0 = blockIdx.y * 128;
    int p0 = blockIdx.x * 64;
    int lane = tid & 63, wv = tid >> 6;
    int wp = wv & 1, wq = wv >> 1;
    int quad = lane >> 4, l15 = lane & 15;

    f32x4 acc[4][2];
    #pragma unroll
    for (int i = 0; i < 4; ++i)
        #pragma unroll
        for (int jq = 0; jq < 2; ++jq) acc[i][jq] = (f32x4){0.f, 0.f, 0.f, 0.f};

    int spx = tid & 63;
    int sk8 = (tid >> 6) * 8;

    for (int kt = 0; kt < K / 32; ++kt) {
        __syncthreads();
        #pragma unroll
        for (int r = 0; r < 2; ++r) {
            int chunk = tid + r * 256;
            int row = chunk >> 2, k8 = (chunk & 3) * 8;
            const float* src = w + (size_t)(n0 + row) * K + kt * 32 + k8;
            float4 f0 = *(const float4*)src;
            float4 f1 = *(const float4*)(src + 4);
            uint4_t u;
            u[0] = pack2(f0.x, f0.y);
            u[1] = pack2(f0.z, f0.w);
            u[2] = pack2(f1.x, f1.y);
            u[3] = pack2(f1.z, f1.w);
            *(uint4_t*)&lds_p[row * LP + k8] = u;
        }
        {
            const float* xcol = x + ((size_t)b * CC + kt * 32 + sk8) * HW + p0 + spx;
            float v0 = xcol[0];
            float v1 = xcol[(size_t)HW];
            float v2 = xcol[(size_t)2 * HW];
            float v3 = xcol[(size_t)3 * HW];
            float v4 = xcol[(size_t)4 * HW];
            float v5 = xcol[(size_t)5 * HW];
            float v6 = xcol[(size_t)6 * HW];
            float v7 = xcol[(size_t)7 * HW];
            uint4_t u;
            u[0] = pack2(v0, v1);
            u[1] = pack2(v2, v3);
            u[2] = pack2(v4, v5);
            u[3] = pack2(v6, v7);
            *(uint4_t*)&lds_q[spx * LP + sk8] = u;
        }
        __syncthreads();
        bf16x8 afrag[4], bfrag[2];
        #pragma unroll
        for (int i = 0; i < 4; ++i)
            afrag[i] = *(const bf16x8*)&lds_p[(wp * 64 + i * 16 + l15) * LP + quad * 8];
        #pragma unroll
        for (int jq = 0; jq < 2; ++jq)
            bfrag[jq] = *(const bf16x8*)&lds_q[(wq * 32 + jq * 16 + l15) * LP + quad * 8];
        #pragma unroll
        for (int i = 0; i < 4; ++i)
            #pragma unroll
            for (int jq = 0; jq < 2; ++jq)
                acc[i][jq] = __builtin_amdgcn_mfma_f32_16x16x32_bf16(afrag[i], bfrag[jq],
                                                                     acc[i][jq], 0, 0, 0);
    }
    const float qscale = 0.17677669529663687f;
    #pragma unroll
    for (int i = 0; i < 4; ++i) {
        int nbase = n0 + wp * 64 + i * 16 + quad * 4;
        int which = nbase >> 9;
        int h = (nbase >> 5) & 15;
        int dch = nbase & 31;
        float sc = (which == 0) ? qscale : 1.0f;
        #pragma unroll
        for (int jq = 0; jq < 2; ++jq) {
            int pix = p0 + wq * 32 + jq * 16 + l15;
            uint2_t v;
            v[0] = pack2(acc[i][jq][0] * sc, acc[i][jq][1] * sc);
            v[1] = pack2(acc[i][jq][2] * sc, acc[i][jq][3] * sc);
            ushort_t* dst = qkv + (size_t)which * PLANE +
                            ((((size_t)b * HEADS + h) * HW + pix) * DD + dch);
            *(uint2_t*)dst = v;
        }
    }
}

// ---------------- MFMA attention: one block per (b, h, 8x8 query tile) ----------------
__global__ __launch_bounds__(256, 4) void attn_mfma(ushort_t* __restrict__ qkv,
                                                    const float* __restrict__ rpb) {
    __shared__ __align__(16) ushort_t Klds[224 * KP];        // 14336 B, [kk][d]
    __shared__ __align__(16) ushort_t Vlds[DD * VPP];        // 14592 B, [d][kk]
    __shared__ float rpbl[169];                              //   676 B

    int tid = threadIdx.x;

    // T1 XCD swizzle: grid 49x16x8 = 6272 = 8 x 784; each XCD chunk = one batch b
    int lid = ((int)blockIdx.z * 16 + (int)blockIdx.y) * 49 + (int)blockIdx.x;
    int wl = (lid & 7) * 784 + (lid >> 3);
    int tile = wl % 49;
    int rest = wl / 49;
    int h = rest % 16;
    int b = rest / 16;

    int ti = tile / 7, tj = tile - ti * 7;
    int i0 = ti * 8, j0 = tj * 8;
    int kr0 = min(max(i0 - 3, 0), HH - 14);
    int kc0 = min(max(j0 - 3, 0), HH - 14);

    const ushort_t* qp = qkv + (((size_t)b * HEADS + h) * HW) * DD;
    const ushort_t* kp = qp + PLANE;
    const ushort_t* vp = qp + 2 * PLANE;

    if (tid < 169) rpbl[tid] = rpb[h * 169 + tid];

    #pragma unroll
    for (int r = 0; r < 4; ++r) {
        int idx = tid + r * 256;
        if (idx < 784) {
            int u = idx / 56;
            int rem = idx - u * 56;
            int w = rem >> 2, d8 = (rem & 3) << 3;
            const ushort_t* src = kp + ((size_t)((kr0 + u) * HH + kc0 + w)) * DD + d8;
            *(uint4_t*)&Klds[(u * 16 + w) * KP + d8] = *(const uint4_t*)src;
        } else if (idx < 896) {
            int z = idx - 784;
            int u = z >> 3, rem = z & 7;
            int w = 14 + (rem >> 2), d8 = (rem & 3) << 3;
            *(uint4_t*)&Klds[(u * 16 + w) * KP + d8] = (uint4_t){0, 0, 0, 0};
        }
    }
    #pragma unroll
    for (int rr = 0; rr < 2; ++rr) {
        int idx = tid + rr * 256;
        if (idx < 448) {
            int u = idx >> 5, rem = idx & 31;
            int pr = rem >> 2, d8 = (rem & 3) << 3;
            int kk0 = u * 16 + pr * 2;
            if (pr < 7) {
                const ushort_t* s0 = vp + ((size_t)((kr0 + u) * HH + kc0 + pr * 2)) * DD + d8;
                uint4_t a = *(const uint4_t*)s0;
                uint4_t c = *(const uint4_t*)(s0 + DD);
                #pragma unroll
                for (int e = 0; e < 4; ++e) {
                    unsigned lo = (a[e] & 0xFFFFu) | (c[e] << 16);
                    unsigned hi = (a[e] >> 16) | (c[e] & 0xFFFF0000u);
                    *(unsigned*)&Vlds[(d8 + 2 * e) * VPP + kk0] = lo;
                    *(unsigned*)&Vlds[(d8 + 2 * e + 1) * VPP + kk0] = hi;
                }
            } else {
                #pragma unroll
                for (int e = 0; e < 8; ++e)
                    *(unsigned*)&Vlds[(d8 + e) * VPP + kk0] = 0;
            }
        }
    }

    int lane = tid & 63, wv = tid >> 6;
    int l15 = lane & 15, quad = lane >> 4;
    int q_idx = wv * 16 + l15;
    int qi = i0 + (q_idx >> 3), qj = j0 + (q_idx & 7);
    int si = min(max(qi - 3, 0), HH - 7);
    int sj = min(max(qj - 3, 0), HH - 7);

    bf16x8 bq = *(const bf16x8*)(qp + ((size_t)(qi * HH + qj)) * DD + quad * 8);

    int jbase = kc0 + quad * 4 - sj;
    int cbase = kc0 + quad * 4 - qj + 6;
    int coff[4];
    bool cok[4];
    #pragma unroll
    for (int r2 = 0; r2 < 4; ++r2) {
        cok[r2] = (unsigned)(jbase + r2) <= 6u;
        coff[r2] = min(max(cbase + r2, 0), 12);
    }

    __syncthreads();

    f32x4 lg[KT];
    f32x4 zf = {0.f, 0.f, 0.f, 0.f};
    __builtin_amdgcn_s_setprio(1);             // T5: QK^T cluster
    #pragma unroll
    for (int t = 0; t < KT; ++t) {
        bf16x8 ak = *(const bf16x8*)&Klds[(t * 16 + l15) * KP + quad * 8];
        lg[t] = __builtin_amdgcn_mfma_f32_16x16x32_bf16(ak, bq, zf, 0, 0, 0);
    }
    __builtin_amdgcn_s_setprio(0);

    int abase = kr0 - qi + 6;
    #pragma unroll
    for (int t = 0; t < KT; ++t) {
        bool rok = (unsigned)(kr0 + t - si) <= 6u;
        int arow = min(max(abase + t, 0), 12);
        const float* br = &rpbl[arow * 13];
        #pragma unroll
        for (int r2 = 0; r2 < 4; ++r2) {
            float bias = br[coff[r2]];
            lg[t][r2] = (rok && cok[r2]) ? lg[t][r2] + bias : -1e30f;
        }
    }

    float m = -1e30f;
    #pragma unroll
    for (int t = 0; t < KT; ++t)
        #pragma unroll
        for (int r2 = 0; r2 < 4; ++r2) m = fmaxf(m, lg[t][r2]);
    m = fmaxf(m, __shfl_xor(m, 16));
    m = fmaxf(m, __shfl_xor(m, 32));
    float s = 0.f;
    #pragma unroll
    for (int t = 0; t < KT; ++t)
        #pragma unroll
        for (int r2 = 0; r2 < 4; ++r2) {
            float e = __expf(lg[t][r2] - m);
            lg[t][r2] = e;
            s += e;
        }
    s += __shfl_xor(s, 16);
    s += __shfl_xor(s, 32);
    float inv = 1.f / s;

    bf16x4 pb[KT];
    #pragma unroll
    for (int t = 0; t < KT; ++t) {
        union { uint2_t u; bf16x4 v; } cv;
        cv.u[0] = pack2(lg[t][0], lg[t][1]);
        cv.u[1] = pack2(lg[t][2], lg[t][3]);
        pb[t] = cv.v;
    }

    f32x4 acc0 = zf, acc1 = zf;
    __builtin_amdgcn_s_setprio(1);             // T5: PV cluster
    #pragma unroll
    for (int t = 0; t < KT; ++t) {
        bf16x4 bv0 = *(const bf16x4*)&Vlds[l15 * VPP + t * 16 + quad * 4];
        bf16x4 bv1 = *(const bf16x4*)&Vlds[(16 + l15) * VPP + t * 16 + quad * 4];
        acc0 = mfma16x16x16(pb[t], bv0, acc0);
        acc1 = mfma16x16x16(pb[t], bv1, acc1);
    }
    __builtin_amdgcn_s_setprio(0);

    ushort_t* op = qkv + (((size_t)b * HEADS + h) * HW) * DD;
    #pragma unroll
    for (int e = 0; e < 4; ++e) {
        float invq = __shfl(inv, quad * 4 + e);
        int q2 = wv * 16 + quad * 4 + e;
        int pix = (i0 + (q2 >> 3)) * HH + j0 + (q2 & 7);
        op[(size_t)pix * DD + l15] = f2bf(acc0[e] * invq);
        op[(size_t)pix * DD + 16 + l15] = f2bf(acc1[e] * invq);
    }
}

// ---------------- GEMM3 (bf16): y = attn_out . wpb^T + b; OUT f32 ----------------
// 64px x 128c tile, BK=64 (8 K-steps, 16 MFMA/step), dbuf + vmcnt(6), XCD swizzle.
__global__ __launch_bounds__(256) void proj_gemm_bf16(const ushort_t* __restrict__ ao,
                                                      const ushort_t* __restrict__ w,
                                                      const float* __restrict__ bias,
                                                      float* __restrict__ out) {
    __shared__ __align__(16) ushort_t lds_p[2][64 * LPQ];    // 2 x  8192 B
    __shared__ __align__(16) ushort_t lds_q[2][128 * LPQ];   // 2 x 16384 B
    int tid = threadIdx.x;

    // T1 XCD swizzle: grid 49x4x8 = 1568 = 8 x 196; each XCD chunk = one batch b
    int lid = ((int)blockIdx.z * 4 + (int)blockIdx.y) * 49 + (int)blockIdx.x;
    int wl = (lid & 7) * 196 + (lid >> 3);
    int p0 = (wl % 49) * 64;
    int rest = wl / 49;
    int c0 = (rest % 4) * 128;
    int b = rest / 4;

    int lane = tid & 63, wv = tid >> 6;
    int wp = wv & 1, wq = wv >> 1;
    int quad = lane >> 4, l15 = lane & 15;

    f32x4 acc[2][4];
    #pragma unroll
    for (int i = 0; i < 2; ++i)
        #pragma unroll
        for (int jq = 0; jq < 4; ++jq) acc[i][jq] = (f32x4){0.f, 0.f, 0.f, 0.f};

    const ushort_t* abase = ao + ((size_t)b * HEADS) * HW * DD;
    int s7 = l15 & 7;

    // A: 64 rows x 64k = 512 chunks (2/thread); rows are pixels, k spans 2 heads
    int ca_row[2], ca_k8[2];
    #pragma unroll
    for (int r = 0; r < 2; ++r) {
        int c = r * 256 + tid;
        ca_row[r] = c >> 3;
        ca_k8[r] = ((c & 7) ^ ((c >> 3) & 7)) * 8;
    }
    // B: 128 rows x 64k = 1024 chunks (4/thread)
    int cb_row[4], cb_k8[4];
    #pragma unroll
    for (int r = 0; r < 4; ++r) {
        int c = r * 256 + tid;
        cb_row[r] = c >> 3;
        cb_k8[r] = ((c & 7) ^ ((c >> 3) & 7)) * 8;
    }

    // A source: global k index ko+ca_k8 spans two consecutive heads
    //   (head = (ko+k)/32, dch = (ko+k)%32); since ca_k8 is a multiple of 8 and
    //   rows are contiguous per head-plane, address = head-plane + pix*DD + dch.
    auto stage = [&](int buf, int ko) {
        #pragma unroll
        for (int r = 0; r < 2; ++r) {
            int gk = ko + ca_k8[r];
            int hh = gk >> 5, dch = gk & 31;
            gload16(abase + ((size_t)hh * HW + p0 + ca_row[r]) * DD + dch,
                    &lds_p[buf][(r * 256 + tid) * 8]);
        }
        #pragma unroll
        for (int r = 0; r < 4; ++r)
            gload16(w + (size_t)(c0 + cb_row[r]) * CC + ko + cb_k8[r],
                    &lds_q[buf][(r * 256 + tid) * 8]);
    };

    auto compute_tile = [&](int cur) {
        #pragma unroll
        for (int kk = 0; kk < 2; ++kk) {
            int cha = ((kk * 4 + quad) ^ s7) * 8;
            bf16x8 afrag[2], bfrag[4];
            #pragma unroll
            for (int i = 0; i < 2; ++i)
                afrag[i] = *(const bf16x8*)&lds_p[cur][(wp * 32 + i * 16 + l15) * LPQ + cha];
            #pragma unroll
            for (int jq = 0; jq < 4; ++jq)
                bfrag[jq] = *(const bf16x8*)&lds_q[cur][(wq * 64 + jq * 16 + l15) * LPQ + cha];
            #pragma unroll
            for (int i = 0; i < 2; ++i)
                #pragma unroll
                for (int jq = 0; jq < 4; ++jq)
                    acc[i][jq] = __builtin_amdgcn_mfma_f32_16x16x32_bf16(afrag[i], bfrag[jq],
                                                                         acc[i][jq], 0, 0, 0);
        }
    };

    const int NKT = CC / 64;                   // 8
    // prologue: stage tile 0 into buffer 0, full drain once
    stage(0, 0);
    asm volatile("s_waitcnt vmcnt(0)" ::: "memory");
    __builtin_amdgcn_s_barrier();
    asm volatile("" ::: "memory");

    for (int kt = 0; kt < NKT - 1; ++kt) {
        int cur = kt & 1;
        stage(cur ^ 1, (kt + 1) * 64);
        // counted wait for tile kt's 6 loads (oldest); kt+1's 6 stay in flight
        asm volatile("s_waitcnt vmcnt(6)" ::: "memory");
        __builtin_amdgcn_s_barrier();
        asm volatile("" ::: "memory");
        compute_tile(cur);
        asm volatile("" ::: "memory");
        __builtin_amdgcn_s_barrier();
        asm volatile("" ::: "memory");
    }
    asm volatile("s_waitcnt vmcnt(0)" ::: "memory");
    __builtin_amdgcn_s_barrier();
    asm volatile("" ::: "memory");
    compute_tile((NKT - 1) & 1);

    #pragma unroll
    for (int i = 0; i < 2; ++i) {
        int pix = p0 + wp * 32 + i * 16 + quad * 4;
        #pragma unroll
        for (int jq = 0; jq < 4; ++jq) {
            int cch = c0 + wq * 64 + jq * 16 + l15;
            float bz = bias[cch];
            float4 v;
            v.x = acc[i][jq][0] + bz;
            v.y = acc[i][jq][1] + bz;
            v.z = acc[i][jq][2] + bz;
            v.w = acc[i][jq][3] + bz;
            float* dst = out + ((size_t)b * CC + cch) * HW + pix;
            *(float4*)dst = v;
        }
    }
}

// ---------------- GEMM3 fallback (f32 w) ----------------
__global__ __launch_bounds__(256) void proj_gemm_kernel(const ushort_t* __restrict__ ao,
                                                        const float* __restrict__ w,
                                                        const float* __restrict__ bias,
                                                        float* __restrict__ out) {
    __shared__ __align__(16) ushort_t lds_p[64 * LP];
    __shared__ __align__(16) ushort_t lds_q[128 * LP];
    const int K = CC;
    int tid = threadIdx.x;
    int b = blockIdx.z;
    int p0 = blockIdx.x * 64;
    int c0 = blockIdx.y * 128;
    int lane = tid & 63, wv = tid >> 6;
    int wp = wv & 1, wq = wv >> 1;
    int quad = lane >> 4, l15 = lane & 15;

    f32x4 acc[2][4];
    #pragma unroll
    for (int i = 0; i < 2; ++i)
        #pragma unroll
        for (int jq = 0; jq < 4; ++jq) acc[i][jq] = (f32x4){0.f, 0.f, 0.f, 0.f};

    const ushort_t* abase = ao + ((size_t)b * HEADS) * HW * DD;

    for (int kt = 0; kt < K / 32; ++kt) {
        __syncthreads();
        {
            int row = tid >> 2, k8 = (tid & 3) * 8;
            uint4_t u = *(const uint4_t*)(abase + ((size_t)kt * HW + p0 + row) * DD + k8);
            *(uint4_t*)&lds_p[row * LP + k8] = u;
        }
        #pragma unroll
        for (int r = 0; r < 2; ++r) {
            int chunk = tid + r * 256;
            int row = chunk >> 2, k8 = (chunk & 3) * 8;
            const float* src = w + (size_t)(c0 + row) * K + kt * 32 + k8;
            float4 f0 = *(const float4*)src;
            float4 f1 = *(const float4*)(src + 4);
            uint4_t u;
            u[0] = pack2(f0.x, f0.y);
            u[1] = pack2(f0.z, f0.w);
            u[2] = pack2(f1.x, f1.y);
            u[3] = pack2(f1.z, f1.w);
            *(uint4_t*)&lds_q[row * LP + k8] = u;
        }
        __syncthreads();
        bf16x8 afrag[2], bfrag[4];
        #pragma unroll
        for (int i = 0; i < 2; ++i)
            afrag[i] = *(const bf16x8*)&lds_p[(wp * 32 + i * 16 + l15) * LP + quad * 8];
        #pragma unroll
        for (int jq = 0; jq < 4; ++jq)
            bfrag[jq] = *(const bf16x8*)&lds_q[(wq * 64 + jq * 16 + l15) * LP + quad * 8];
        #pragma unroll
        for (int i = 0; i < 2; ++i)
            #pragma unroll
            for (int jq = 0; jq < 4; ++jq)
                acc[i][jq] = __builtin_amdgcn_mfma_f32_16x16x32_bf16(afrag[i], bfrag[jq],
                                                                     acc[i][jq], 0, 0, 0);
    }
    #pragma unroll
    for (int i = 0; i < 2; ++i) {
        int pix = p0 + wp * 32 + i * 16 + quad * 4;
        #pragma unroll
        for (int jq = 0; jq < 4; ++jq) {
            int cch = c0 + wq * 64 + jq * 16 + l15;
            float bz = bias[cch];
            float4 v;
            v.x = acc[i][jq][0] + bz;
            v.y = acc[i][jq][1] + bz;
            v.z = acc[i][jq][2] + bz;
            v.w = acc[i][jq][3] + bz;
            float* dst = out + ((size_t)b * CC + cch) * HW + pix;
            *(float4*)dst = v;
        }
    }
}

extern "C" void kernel_launch(void* const* d_in, const int* in_sizes, int n_in,
                              void* d_out, int out_size, void* d_ws, size_t ws_size,
                              hipStream_t stream) {
    const float* x = (const float*)d_in[0];
    const float* qkv_w = (const float*)d_in[1];
    const float* rpb = (const float*)d_in[2];
    const float* proj_w = (const float*)d_in[3];
    const float* proj_b = (const float*)d_in[4];
    float* out = (float*)d_out;

    size_t need_min = 3 * PLANE * sizeof(ushort_t);                       // 73.5 MB
    size_t need_full = (4 * PLANE + WQ_ELEMS + WP_ELEMS) * sizeof(ushort_t);  // 100 MB

    if (ws_size < need_min) {
        zero_out_f32<<<dim3((int)((OUT_TOT + 255) / 256)), dim3(256), 0, stream>>>(out);
        return;
    }

    ushort_t* qkv = (ushort_t*)d_ws;                 // q/k/v: 3 bf16 planes

    if (ws_size >= need_full) {
        ushort_t* xbf = qkv + 3 * PLANE;             // bf16 x, [b][hw][c] (TRANSPOSED)
        ushort_t* wqb = qkv + 4 * PLANE;             // bf16 qkv_w
        ushort_t* wpb = wqb + WQ_ELEMS;              // bf16 proj_w

        xpose_cvt<<<dim3(49, 8, 8), dim3(256), 0, stream>>>(x, xbf);
        cvt_weights<<<dim3((WQ_ELEMS / 8 + WP_ELEMS / 8 + 255) / 256), dim3(256), 0,
                      stream>>>(qkv_w, wqb, WQ_ELEMS / 8, proj_w, wpb, WP_ELEMS / 8);

        qkv_gemm_bf16<<<dim3(49, 6, 8), dim3(256), 0, stream>>>(xbf, wqb, qkv);
        attn_mfma<<<dim3(49, HEADS, BATCH), dim3(256), 0, stream>>>(qkv, rpb);
        proj_gemm_bf16<<<dim3(49, 4, 8), dim3(256), 0, stream>>>(qkv, wpb, proj_b, out);
    } else {
        qkv_gemm_kernel<<<dim3(49, 12, 8), dim3(256), 0, stream>>>(x, qkv_w, qkv);
        attn_mfma<<<dim3(49, HEADS, BATCH), dim3(256), 0, stream>>>(qkv, rpb);
        proj_gemm_kernel<<<dim3(49, 4, 8), dim3(256), 0, stream>>>(qkv, proj_w, proj_b, out);
    }
}